// Round 4
// baseline (529.875 us; speedup 1.0000x reference)
//
#include <hip/hip_runtime.h>
#include <math.h>

#define CH     128
#define EPSV   1e-5f
#define SCALE  0.17677669529663687f   // 32^-0.5
#define GSIZE  262144.0f

// ---------------- group-norm partial stats (2048 blocks x 8192 elems) ----------------
__global__ __launch_bounds__(256) void gn_partial(const float* __restrict__ x,
                                                  float* __restrict__ part) {
    __shared__ float s1[256], s2[256];
    int t = threadIdx.x;
    const float4* xp = (const float4*)(x + (size_t)blockIdx.x * 8192);
    float s = 0.f, q = 0.f;
#pragma unroll
    for (int i = 0; i < 8; ++i) {
        float4 v = xp[t + 256 * i];
        s += v.x + v.y + v.z + v.w;
        q += v.x * v.x + v.y * v.y + v.z * v.z + v.w * v.w;
    }
    s1[t] = s; s2[t] = q;
    __syncthreads();
    for (int st = 128; st > 0; st >>= 1) {
        if (t < st) { s1[t] += s1[t + st]; s2[t] += s2[t + st]; }
        __syncthreads();
    }
    if (t == 0) { part[2 * blockIdx.x] = s1[0]; part[2 * blockIdx.x + 1] = s2[0]; }
}

// ---------------- finalize gn1 stats ---------------------------------------------------
__global__ void prep1(const float* __restrict__ part, float* __restrict__ mu, float* __restrict__ rs) {
    int t = threadIdx.x;   // 64 threads
    float s = 0.f, q = 0.f;
    for (int i = 0; i < 32; ++i) { s += part[2*(t*32+i)]; q += part[2*(t*32+i)+1]; }
    float m = s * (1.f / GSIZE);
    float v = q * (1.f / GSIZE) - m * m;
    mu[t] = m; rs[t] = rsqrtf(v + EPSV);
}

// ---------------- k/v pass: 512 thr, 4x8 micro-tile, 9 persistent regs, no spill -------
// grid 512; block bi handles tiles bi*4 .. bi*4+3 (64 positions each), batch bi>>8.
__global__ __launch_bounds__(512, 4) void kv_pass(const float* __restrict__ x,
        const float* __restrict__ w_qkv,
        const float* __restrict__ n1w, const float* __restrict__ n1b,
        const float* __restrict__ mu, const float* __restrict__ rs,
        float* __restrict__ part_kv) {
    __shared__ union {
        struct { float xns[128][68]; float wsmT[16][260]; } a;
        float kvs[17408];          // [256 rows][68], 4-float granules XOR-swizzled by (row>>3)&7
    } sm;
    int tid = threadIdx.x;
    int rt = tid >> 3, nt = tid & 7;                 // GEMM: 64 rt x 8 nt (4x8 micro-tile)
    int h = tid >> 7, l = tid & 127;                 // ctx: 4 h x (32 d x 4 e-quarters)
    int d = l >> 2, eq = l & 3;
    int krow = h*32 + d, swk = (krow >> 3) & 7;

    float cacc[8];
    float zacc = 0.f;
#pragma unroll
    for (int e = 0; e < 8; ++e) cacc[e] = 0.f;

    int b = blockIdx.x >> 8;

    for (int t4 = 0; t4 < 4; ++t4) {
        int n0 = ((blockIdx.x * 4 + t4) << 6) & 65535;

        // stage + normalize x tile (128 ch x 64 pos) : 2048 float4 / 512 thr
#pragma unroll
        for (int it = 0; it < 4; ++it) {
            int fi = it * 512 + tid;
            int c = fi >> 4, nq = fi & 15;
            float4 v = *(const float4*)(x + ((b*CH + c) << 16) + n0 + nq*4);
            int fg = b*32 + (c >> 2);
            float aa = rs[fg] * n1w[c];
            float bb = n1b[c] - mu[fg] * aa;
            *(float4*)&sm.a.xns[c][nq*4] =
                make_float4(v.x*aa+bb, v.y*aa+bb, v.z*aa+bb, v.w*aa+bb);
        }

        float acc[4][8];
#pragma unroll
        for (int i = 0; i < 4; ++i)
#pragma unroll
            for (int j = 0; j < 8; ++j) acc[i][j] = 0.f;

        for (int cc = 0; cc < 128; cc += 16) {
            __syncthreads();
#pragma unroll
            for (int it = 0; it < 2; ++it) {         // stage w_qkv rows 128..383, 16 cols, transposed
                int fi = it * 512 + tid;             // 1024 float4
                int r = fi >> 2, cq = fi & 3;
                float4 v = *(const float4*)(w_qkv + (128 + r)*CH + cc + cq*4);
                sm.a.wsmT[cq*4+0][r] = v.x;
                sm.a.wsmT[cq*4+1][r] = v.y;
                sm.a.wsmT[cq*4+2][r] = v.z;
                sm.a.wsmT[cq*4+3][r] = v.w;
            }
            __syncthreads();
#pragma unroll
            for (int k = 0; k < 16; ++k) {
                float4 w0 = *(float4*)&sm.a.wsmT[k][rt*4];
                float4 x0 = *(float4*)&sm.a.xns[cc+k][nt*8];
                float4 x1 = *(float4*)&sm.a.xns[cc+k][nt*8+4];
                float rw[4] = {w0.x,w0.y,w0.z,w0.w};
                float xv[8] = {x0.x,x0.y,x0.z,x0.w,x1.x,x1.y,x1.z,x1.w};
#pragma unroll
                for (int i = 0; i < 4; ++i)
#pragma unroll
                    for (int j = 0; j < 8; ++j) acc[i][j] += rw[i]*xv[j];
            }
        }
        __syncthreads();                 // GEMM LDS reads done before union overwrite

        // write exp(k)/v into kvs (row-major, granule-swizzled)
#pragma unroll
        for (int i = 0; i < 4; ++i) {
            int row = rt*4 + i;
            int swr = (row >> 3) & 7;
            float4 lo, hi;
            if (row < 128) {
                lo = make_float4(expf(acc[i][0]), expf(acc[i][1]), expf(acc[i][2]), expf(acc[i][3]));
                hi = make_float4(expf(acc[i][4]), expf(acc[i][5]), expf(acc[i][6]), expf(acc[i][7]));
            } else {
                lo = make_float4(acc[i][0], acc[i][1], acc[i][2], acc[i][3]);
                hi = make_float4(acc[i][4], acc[i][5], acc[i][6], acc[i][7]);
            }
            int g0 = (2*nt) ^ swr, g1 = (2*nt + 1) ^ swr;
            *(float4*)&sm.kvs[row*68 + g0*4] = lo;
            *(float4*)&sm.kvs[row*68 + g1*4] = hi;
        }
        __syncthreads();

        // ctx accumulate: thread = (h, d, eq) over all 64 nn of this tile
#pragma unroll
        for (int g = 0; g < 16; ++g) {
            float4 ek = *(float4*)&sm.kvs[krow*68 + ((g ^ swk) << 2)];
            if (eq == 0) zacc += ek.x + ek.y + ek.z + ek.w;
#pragma unroll
            for (int i = 0; i < 8; ++i) {
                int vrow = 128 + h*32 + eq*8 + i;
                float4 vv = *(float4*)&sm.kvs[vrow*68 + ((g ^ ((vrow>>3)&7)) << 2)];
                cacc[i] += ek.x*vv.x + ek.y*vv.y + ek.z*vv.z + ek.w*vv.w;
            }
        }
        __syncthreads();                 // kvs reads done before next tile's xns staging
    }

    // direct streaming partial write (single copy per thread, no merge needed)
    float* dst = part_kv + (size_t)blockIdx.x * 4224 + h*1024 + d*32 + eq*8;
    *(float4*)&dst[0] = make_float4(cacc[0], cacc[1], cacc[2], cacc[3]);
    *(float4*)&dst[4] = make_float4(cacc[4], cacc[5], cacc[6], cacc[7]);
    if (eq == 0) part_kv[(size_t)blockIdx.x * 4224 + 4096 + krow] = zacc;
}

// ---------------- reduce partials + memory-kv init -> ctx, Z ---------------------------
__global__ void reduce_ctx(const float* __restrict__ part_kv, const float* __restrict__ mem_kv,
                           float* __restrict__ ctx, float* __restrict__ Z) {
    int gid = blockIdx.x * 256 + threadIdx.x;   // 0..8447
    int b = gid / 4224;
    int e = gid - b * 4224;
    const float* p = part_kv + (size_t)b * 256 * 4224 + e;
    float s0 = 0.f, s1 = 0.f, s2 = 0.f, s3 = 0.f;
    for (int i = 0; i < 256; i += 4) {
        s0 += p[(i+0)*4224];
        s1 += p[(i+1)*4224];
        s2 += p[(i+2)*4224];
        s3 += p[(i+3)*4224];
    }
    float s = (s0 + s1) + (s2 + s3);
    if (e < 4096) {
        int hh = e >> 10, d = (e >> 5) & 31, ee = e & 31;
        float init = 0.f;
        for (int m = 0; m < 4; ++m)
            init += expf(mem_kv[hh*128 + d*4 + m]) * mem_kv[512 + hh*128 + ee*4 + m];
        ctx[b*4096 + e] = init + s;
    } else {
        int d2 = e - 4096;
        float init = 0.f;
        for (int m = 0; m < 4; ++m) init += expf(mem_kv[d2*4 + m]);
        Z[b*128 + d2] = init + s;
    }
}

// ---------------- out pass: q GEMM -> softmax(d) -> ctx apply -> w_out GEMM + gn2 part --
__global__ __launch_bounds__(256, 2) void out_pass(const float* __restrict__ x,
        const float* __restrict__ w_qkv,
        const float* __restrict__ n1w, const float* __restrict__ n1b,
        const float* __restrict__ mu, const float* __restrict__ rs,
        const float* __restrict__ ctx, const float* __restrict__ Z,
        const float* __restrict__ w_out, const float* __restrict__ b_out,
        float* __restrict__ out, float* __restrict__ part2) {
    __shared__ union { float xns[128][64]; float hid[128][64]; } ra;
    __shared__ union { float wsm[128][17]; float ctxs[4][32][32]; } rb;
    __shared__ float qs[128][64];
    int tid = threadIdx.x;
    int p0 = blockIdx.x << 6;
    int b  = p0 >> 16;
    int n0 = p0 & 65535;

#pragma unroll
    for (int it = 0; it < 8; ++it) {
        int fi = it * 256 + tid;
        int c = fi >> 4, nq = fi & 15;
        float4 v = *(const float4*)(x + ((b*CH + c) << 16) + n0 + nq*4);
        int fg = b*32 + (c >> 2);
        float aa = rs[fg] * n1w[c];
        float bb = n1b[c] - mu[fg] * aa;
        ra.xns[c][nq*4+0] = v.x*aa+bb;
        ra.xns[c][nq*4+1] = v.y*aa+bb;
        ra.xns[c][nq*4+2] = v.z*aa+bb;
        ra.xns[c][nq*4+3] = v.w*aa+bb;
    }

    float acc[4][8];
#pragma unroll
    for (int i = 0; i < 4; ++i)
#pragma unroll
        for (int j = 0; j < 8; ++j) acc[i][j] = 0.f;
    int rt = tid >> 3, nt = tid & 7;
    for (int cc = 0; cc < 128; cc += 16) {    // q GEMM: w_qkv rows 0..127
        __syncthreads();
#pragma unroll
        for (int it = 0; it < 2; ++it) {
            int fi = it * 256 + tid;
            int r = fi >> 2, cq = fi & 3;
            float4 v = *(const float4*)(w_qkv + r*CH + cc + cq*4);
            rb.wsm[r][cq*4+0] = v.x;
            rb.wsm[r][cq*4+1] = v.y;
            rb.wsm[r][cq*4+2] = v.z;
            rb.wsm[r][cq*4+3] = v.w;
        }
        __syncthreads();
#pragma unroll
        for (int k = 0; k < 16; ++k) {
            float rw[4], xv[8];
#pragma unroll
            for (int i = 0; i < 4; ++i) rw[i] = rb.wsm[rt*4+i][k];
#pragma unroll
            for (int j = 0; j < 8; ++j) xv[j] = ra.xns[cc+k][nt*8+j];
#pragma unroll
            for (int i = 0; i < 4; ++i)
#pragma unroll
                for (int j = 0; j < 8; ++j) acc[i][j] += rw[i]*xv[j];
        }
    }
    __syncthreads();
#pragma unroll
    for (int i = 0; i < 4; ++i)
#pragma unroll
        for (int j = 0; j < 8; ++j) qs[rt*4+i][nt*8+j] = acc[i][j];
    for (int idx = tid; idx < 4096; idx += 256) {
        int e = idx & 31, dd = (idx >> 5) & 31, h2 = idx >> 10;
        rb.ctxs[h2][dd][e] = ctx[b*4096 + idx] / Z[b*128 + h2*32 + dd];
    }
    __syncthreads();

    {   // softmax over d per (h,n) column
        int h2 = tid >> 6, n = tid & 63;
        float pv[32]; float ssum = 0.f;
#pragma unroll
        for (int dd = 0; dd < 32; ++dd) { pv[dd] = expf(qs[h2*32+dd][n]); ssum += pv[dd]; }
        float inv = SCALE / ssum;
#pragma unroll
        for (int dd = 0; dd < 32; ++dd) qs[h2*32+dd][n] = pv[dd] * inv;
    }
    __syncthreads();

    {   // hid[e][n] = sum_d ctx[d][e] * qprob[d][n]   (per head)
        int h2 = tid >> 6, l = tid & 63;
        int et = l >> 3, nt2 = l & 7;
        float a3[4][8];
#pragma unroll
        for (int i = 0; i < 4; ++i)
#pragma unroll
            for (int j = 0; j < 8; ++j) a3[i][j] = 0.f;
#pragma unroll
        for (int dd = 0; dd < 32; ++dd) {
            float4 cv = *(const float4*)&rb.ctxs[h2][dd][et*4];
            float rw[4] = {cv.x, cv.y, cv.z, cv.w};
            float xv[8];
#pragma unroll
            for (int j = 0; j < 8; ++j) xv[j] = qs[h2*32+dd][nt2*8+j];
#pragma unroll
            for (int i = 0; i < 4; ++i)
#pragma unroll
                for (int j = 0; j < 8; ++j) a3[i][j] += rw[i]*xv[j];
        }
#pragma unroll
        for (int i = 0; i < 4; ++i)
#pragma unroll
            for (int j = 0; j < 8; ++j) ra.hid[h2*32 + et*4 + i][nt2*8 + j] = a3[i][j];
    }

    float a2[4][8];
#pragma unroll
    for (int i = 0; i < 4; ++i)
#pragma unroll
        for (int j = 0; j < 8; ++j) a2[i][j] = 0.f;
    for (int cc = 0; cc < 128; cc += 16) {     // final GEMM: w_out @ hid
        __syncthreads();
#pragma unroll
        for (int it = 0; it < 2; ++it) {
            int fi = it * 256 + tid;
            int r = fi >> 2, cq = fi & 3;
            float4 v = *(const float4*)(w_out + r*CH + cc + cq*4);
            rb.wsm[r][cq*4+0] = v.x;
            rb.wsm[r][cq*4+1] = v.y;
            rb.wsm[r][cq*4+2] = v.z;
            rb.wsm[r][cq*4+3] = v.w;
        }
        __syncthreads();
#pragma unroll
        for (int k = 0; k < 16; ++k) {
            float rw[4], hv[8];
#pragma unroll
            for (int i = 0; i < 4; ++i) rw[i] = rb.wsm[rt*4+i][k];
#pragma unroll
            for (int j = 0; j < 8; ++j) hv[j] = ra.hid[cc+k][nt*8+j];
#pragma unroll
            for (int i = 0; i < 4; ++i)
#pragma unroll
                for (int j = 0; j < 8; ++j) a2[i][j] += rw[i]*hv[j];
        }
    }

    float gs = 0.f, gq = 0.f;
#pragma unroll
    for (int i = 0; i < 4; ++i) {
        int c = rt*4 + i;
        float bo = b_out[c];
        float o[8];
#pragma unroll
        for (int j = 0; j < 8; ++j) { o[j] = a2[i][j] + bo; gs += o[j]; gq += o[j]*o[j]; }
        float* dst = out + ((b*CH + c) << 16) + n0 + nt*8;
        *(float4*)dst       = make_float4(o[0], o[1], o[2], o[3]);
        *(float4*)(dst + 4) = make_float4(o[4], o[5], o[6], o[7]);
    }
    // gn2 partial: reduce over the 8 nt threads of each rt (group = rt)
    float2* rbuf = (float2*)&qs[0][0];
    rbuf[rt*8 + nt] = make_float2(gs, gq);
    __syncthreads();
    if (tid < 32) {
        float ss = 0.f, qq = 0.f;
#pragma unroll
        for (int k2 = 0; k2 < 8; ++k2) { float2 v = rbuf[tid*8 + k2]; ss += v.x; qq += v.y; }
        part2[blockIdx.x*64 + tid*2 + 0] = ss;
        part2[blockIdx.x*64 + tid*2 + 1] = qq;
    }
}

// ---------------- gn2 finalize --------------------------------------------------------
__global__ __launch_bounds__(256) void reduce2(const float* __restrict__ part2,
                                               float* __restrict__ mu, float* __restrict__ rs) {
    __shared__ float s1[256], s2[256];
    int fg = blockIdx.x;          // 0..63
    int b = fg >> 5, g = fg & 31;
    int t = threadIdx.x;
    float s = 0.f, q = 0.f;
    for (int i = t; i < 1024; i += 256) {
        const float* p = part2 + (size_t)(b*1024 + i)*64 + g*2;
        s += p[0]; q += p[1];
    }
    s1[t] = s; s2[t] = q;
    __syncthreads();
    for (int st = 128; st > 0; st >>= 1) {
        if (t < st) { s1[t] += s1[t + st]; s2[t] += s2[t + st]; }
        __syncthreads();
    }
    if (t == 0) {
        float m = s1[0] * (1.f / GSIZE);
        float v = s2[0] * (1.f / GSIZE) - m*m;
        mu[fg] = m; rs[fg] = rsqrtf(v + EPSV);
    }
}

__global__ __launch_bounds__(256) void gn_apply(float* __restrict__ y,
        const float* __restrict__ mu, const float* __restrict__ rs,
        const float* __restrict__ w2, const float* __restrict__ b2) {
    int bi = blockIdx.x, t = threadIdx.x;
    int c = (bi >> 3) & 127;
    int b = bi >> 10;
    int fg = b*32 + (c >> 2);
    float aa = rs[fg] * w2[c];
    float bb = b2[c] - mu[fg] * aa;
    float4* yp = (float4*)(y + (size_t)bi * 8192);
#pragma unroll
    for (int i = 0; i < 8; ++i) {
        float4 v = yp[t + 256*i];
        v.x = v.x*aa+bb; v.y = v.y*aa+bb; v.z = v.z*aa+bb; v.w = v.w*aa+bb;
        yp[t + 256*i] = v;
    }
}

extern "C" void kernel_launch(void* const* d_in, const int* in_sizes, int n_in,
                              void* d_out, int out_size, void* d_ws, size_t ws_size,
                              hipStream_t stream) {
    (void)in_sizes; (void)n_in; (void)out_size; (void)ws_size;
    const float* x      = (const float*)d_in[0];
    const float* n1w    = (const float*)d_in[1];
    const float* n1b    = (const float*)d_in[2];
    const float* w_qkv  = (const float*)d_in[3];
    const float* mem_kv = (const float*)d_in[4];
    const float* w_out  = (const float*)d_in[5];
    const float* b_out  = (const float*)d_in[6];
    const float* n2w    = (const float*)d_in[7];
    const float* n2b    = (const float*)d_in[8];
    float* out = (float*)d_out;
    float* ws  = (float*)d_ws;

    float* part1   = ws;              // 4096
    float* mu1     = ws + 4096;       // 64
    float* rs1     = ws + 4160;       // 64
    float* ctx     = ws + 4224;       // 8192
    float* Z       = ws + 12416;      // 256
    float* part2   = ws + 12672;      // 2048*64 = 131072
    float* mu2     = ws + 143744;     // 64
    float* rs2     = ws + 143808;     // 64
    float* part_kv = ws + 143872;     // 512*4224 = 2162688  (total ~9.2 MB)

    gn_partial<<<2048, 256, 0, stream>>>(x, part1);
    prep1<<<1, 64, 0, stream>>>(part1, mu1, rs1);
    kv_pass<<<512, 512, 0, stream>>>(x, w_qkv, n1w, n1b, mu1, rs1, part_kv);
    reduce_ctx<<<33, 256, 0, stream>>>(part_kv, mem_kv, ctx, Z);
    out_pass<<<2048, 256, 0, stream>>>(x, w_qkv, n1w, n1b, mu1, rs1, ctx, Z, w_out, b_out, out, part2);
    reduce2<<<64, 256, 0, stream>>>(part2, mu2, rs2);
    gn_apply<<<2048, 256, 0, stream>>>(out, mu2, rs2, n2w, n2b);
}

// Round 5
// 527.880 us; speedup vs baseline: 1.0038x; 1.0038x over previous
//
#include <hip/hip_runtime.h>
#include <math.h>

#define CH     128
#define EPSV   1e-5f
#define SCALE  0.17677669529663687f   // 32^-0.5
#define GSIZE  262144.0f

// ---------------- group-norm partial stats (2048 blocks x 8192 elems) ----------------
__global__ __launch_bounds__(256) void gn_partial(const float* __restrict__ x,
                                                  float* __restrict__ part) {
    __shared__ float s1[256], s2[256];
    int t = threadIdx.x;
    const float4* xp = (const float4*)(x + (size_t)blockIdx.x * 8192);
    float s = 0.f, q = 0.f;
#pragma unroll
    for (int i = 0; i < 8; ++i) {
        float4 v = xp[t + 256 * i];
        s += v.x + v.y + v.z + v.w;
        q += v.x * v.x + v.y * v.y + v.z * v.z + v.w * v.w;
    }
    s1[t] = s; s2[t] = q;
    __syncthreads();
    for (int st = 128; st > 0; st >>= 1) {
        if (t < st) { s1[t] += s1[t + st]; s2[t] += s2[t + st]; }
        __syncthreads();
    }
    if (t == 0) { part[2 * blockIdx.x] = s1[0]; part[2 * blockIdx.x + 1] = s2[0]; }
}

// ---------------- finalize gn1 stats ---------------------------------------------------
__global__ void prep1(const float* __restrict__ part, float* __restrict__ mu, float* __restrict__ rs) {
    int t = threadIdx.x;   // 64 threads
    float s = 0.f, q = 0.f;
    for (int i = 0; i < 32; ++i) { s += part[2*(t*32+i)]; q += part[2*(t*32+i)+1]; }
    float m = s * (1.f / GSIZE);
    float v = q * (1.f / GSIZE) - m * m;
    mu[t] = m; rs[t] = rsqrtf(v + EPSV);
}

// ---------------- k/v pass: per-block partial ctx/Z; NO occupancy cap (spill-free) -----
// grid 512; block bi handles tiles bi*4 .. bi*4+3 (64 positions each), batch bi>>8.
// NOTE: do NOT add a min-occupancy arg to __launch_bounds__ here. (256,2) capped VGPR
// at 128 and (512,4) at 64 -> persistent cacc/zacc spilled to scratch (+170 MB HBM
// traffic, 2.5x kernel time). LDS (69.6 KB) limits us to 2 blocks/CU regardless.
__global__ __launch_bounds__(256) void kv_pass(const float* __restrict__ x,
        const float* __restrict__ w_qkv,
        const float* __restrict__ n1w, const float* __restrict__ n1b,
        const float* __restrict__ mu, const float* __restrict__ rs,
        float* __restrict__ part_kv) {
    __shared__ union {
        struct { float xns[128][68]; float wsmT[16][260]; } a;
        float kvs[17408];          // [256 rows][68], 4-float granules XOR-swizzled by (row>>3)&7
    } sm;
    int tid = threadIdx.x;
    int rt = tid >> 3, nt = tid & 7;                 // GEMM micro-tile coords
    int h = tid >> 6, l = tid & 63;                  // ctx-phase coords
    int d = l >> 1, eh = l & 1;
    int krow = h*32 + d, swk = (krow >> 3) & 7;

    float cacc[16];
    float zacc = 0.f;
#pragma unroll
    for (int e = 0; e < 16; ++e) cacc[e] = 0.f;

    int b = blockIdx.x >> 8;

    for (int t4 = 0; t4 < 4; ++t4) {
        int n0 = ((blockIdx.x * 4 + t4) << 6) & 65535;

        // stage + normalize x tile (128 ch x 64 pos)
#pragma unroll
        for (int it = 0; it < 8; ++it) {
            int fi = it * 256 + tid;
            int c = fi >> 4, nq = fi & 15;
            float4 v = *(const float4*)(x + ((b*CH + c) << 16) + n0 + nq*4);
            int fg = b*32 + (c >> 2);
            float aa = rs[fg] * n1w[c];
            float bb = n1b[c] - mu[fg] * aa;
            *(float4*)&sm.a.xns[c][nq*4] =
                make_float4(v.x*aa+bb, v.y*aa+bb, v.z*aa+bb, v.w*aa+bb);
        }

        float acc[8][8];
#pragma unroll
        for (int i = 0; i < 8; ++i)
#pragma unroll
            for (int j = 0; j < 8; ++j) acc[i][j] = 0.f;

        for (int cc = 0; cc < 128; cc += 16) {
            __syncthreads();
#pragma unroll
            for (int it = 0; it < 4; ++it) {         // stage w_qkv rows 128..383, 16 cols, transposed
                int fi = it * 256 + tid;
                int r = fi >> 2, cq = fi & 3;
                float4 v = *(const float4*)(w_qkv + (128 + r)*CH + cc + cq*4);
                sm.a.wsmT[cq*4+0][r] = v.x;
                sm.a.wsmT[cq*4+1][r] = v.y;
                sm.a.wsmT[cq*4+2][r] = v.z;
                sm.a.wsmT[cq*4+3][r] = v.w;
            }
            __syncthreads();
#pragma unroll
            for (int k = 0; k < 16; ++k) {
                float4 w0 = *(float4*)&sm.a.wsmT[k][rt*8];
                float4 w1 = *(float4*)&sm.a.wsmT[k][rt*8+4];
                float4 x0 = *(float4*)&sm.a.xns[cc+k][nt*8];
                float4 x1 = *(float4*)&sm.a.xns[cc+k][nt*8+4];
                float rw[8] = {w0.x,w0.y,w0.z,w0.w,w1.x,w1.y,w1.z,w1.w};
                float xv[8] = {x0.x,x0.y,x0.z,x0.w,x1.x,x1.y,x1.z,x1.w};
#pragma unroll
                for (int i = 0; i < 8; ++i)
#pragma unroll
                    for (int j = 0; j < 8; ++j) acc[i][j] += rw[i]*xv[j];
            }
        }
        __syncthreads();                 // GEMM LDS reads done before union overwrite

        // write exp(k)/v into kvs (row-major, granule-swizzled)
        int sw = rt & 7;
#pragma unroll
        for (int i = 0; i < 8; ++i) {
            int row = rt*8 + i;
            float4 lo, hi;
            if (row < 128) {
                lo = make_float4(expf(acc[i][0]), expf(acc[i][1]), expf(acc[i][2]), expf(acc[i][3]));
                hi = make_float4(expf(acc[i][4]), expf(acc[i][5]), expf(acc[i][6]), expf(acc[i][7]));
            } else {
                lo = make_float4(acc[i][0], acc[i][1], acc[i][2], acc[i][3]);
                hi = make_float4(acc[i][4], acc[i][5], acc[i][6], acc[i][7]);
            }
            int g0 = (2*nt) ^ sw, g1 = (2*nt + 1) ^ sw;
            *(float4*)&sm.kvs[row*68 + g0*4] = lo;
            *(float4*)&sm.kvs[row*68 + g1*4] = hi;
        }
        __syncthreads();

        // ctx accumulate: thread = (h, d, eh) over all 64 nn of this tile
#pragma unroll
        for (int g = 0; g < 16; ++g) {
            float4 ek = *(float4*)&sm.kvs[krow*68 + ((g ^ swk) << 2)];
            zacc += ek.x + ek.y + ek.z + ek.w;
#pragma unroll
            for (int i = 0; i < 16; ++i) {
                int vrow = 128 + h*32 + eh*16 + i;
                float4 vv = *(float4*)&sm.kvs[vrow*68 + ((g ^ ((vrow>>3)&7)) << 2)];
                cacc[i] += ek.x*vv.x + ek.y*vv.y + ek.z*vv.z + ek.w*vv.w;
            }
        }
        __syncthreads();                 // kvs reads done before next tile's xns staging
    }

    // direct streaming partial write (single copy per thread, no merge needed)
    float* dst = part_kv + (size_t)blockIdx.x * 4224 + h*1024 + d*32 + eh*16;
    *(float4*)&dst[0]  = make_float4(cacc[0],  cacc[1],  cacc[2],  cacc[3]);
    *(float4*)&dst[4]  = make_float4(cacc[4],  cacc[5],  cacc[6],  cacc[7]);
    *(float4*)&dst[8]  = make_float4(cacc[8],  cacc[9],  cacc[10], cacc[11]);
    *(float4*)&dst[12] = make_float4(cacc[12], cacc[13], cacc[14], cacc[15]);
    if (eh == 0) part_kv[(size_t)blockIdx.x * 4224 + 4096 + krow] = zacc;
}

// ---------------- reduce partials + memory-kv init -> ctx, Z ---------------------------
__global__ void reduce_ctx(const float* __restrict__ part_kv, const float* __restrict__ mem_kv,
                           float* __restrict__ ctx, float* __restrict__ Z) {
    int gid = blockIdx.x * 256 + threadIdx.x;   // 0..8447
    int b = gid / 4224;
    int e = gid - b * 4224;
    const float* p = part_kv + (size_t)b * 256 * 4224 + e;
    float s0 = 0.f, s1 = 0.f, s2 = 0.f, s3 = 0.f;
    for (int i = 0; i < 256; i += 4) {
        s0 += p[(i+0)*4224];
        s1 += p[(i+1)*4224];
        s2 += p[(i+2)*4224];
        s3 += p[(i+3)*4224];
    }
    float s = (s0 + s1) + (s2 + s3);
    if (e < 4096) {
        int hh = e >> 10, d = (e >> 5) & 31, ee = e & 31;
        float init = 0.f;
        for (int m = 0; m < 4; ++m)
            init += expf(mem_kv[hh*128 + d*4 + m]) * mem_kv[512 + hh*128 + ee*4 + m];
        ctx[b*4096 + e] = init + s;
    } else {
        int d2 = e - 4096;
        float init = 0.f;
        for (int m = 0; m < 4; ++m) init += expf(mem_kv[d2*4 + m]);
        Z[b*128 + d2] = init + s;
    }
}

// ---------------- out pass: q GEMM -> softmax(d) -> ctx apply -> w_out GEMM + gn2 part --
__global__ __launch_bounds__(256, 2) void out_pass(const float* __restrict__ x,
        const float* __restrict__ w_qkv,
        const float* __restrict__ n1w, const float* __restrict__ n1b,
        const float* __restrict__ mu, const float* __restrict__ rs,
        const float* __restrict__ ctx, const float* __restrict__ Z,
        const float* __restrict__ w_out, const float* __restrict__ b_out,
        float* __restrict__ out, float* __restrict__ part2) {
    __shared__ union { float xns[128][64]; float hid[128][64]; } ra;
    __shared__ union { float wsm[128][17]; float ctxs[4][32][32]; } rb;
    __shared__ float qs[128][64];
    int tid = threadIdx.x;
    int p0 = blockIdx.x << 6;
    int b  = p0 >> 16;
    int n0 = p0 & 65535;

#pragma unroll
    for (int it = 0; it < 8; ++it) {
        int fi = it * 256 + tid;
        int c = fi >> 4, nq = fi & 15;
        float4 v = *(const float4*)(x + ((b*CH + c) << 16) + n0 + nq*4);
        int fg = b*32 + (c >> 2);
        float aa = rs[fg] * n1w[c];
        float bb = n1b[c] - mu[fg] * aa;
        ra.xns[c][nq*4+0] = v.x*aa+bb;
        ra.xns[c][nq*4+1] = v.y*aa+bb;
        ra.xns[c][nq*4+2] = v.z*aa+bb;
        ra.xns[c][nq*4+3] = v.w*aa+bb;
    }

    float acc[4][8];
#pragma unroll
    for (int i = 0; i < 4; ++i)
#pragma unroll
        for (int j = 0; j < 8; ++j) acc[i][j] = 0.f;
    int rt = tid >> 3, nt = tid & 7;
    for (int cc = 0; cc < 128; cc += 16) {    // q GEMM: w_qkv rows 0..127
        __syncthreads();
#pragma unroll
        for (int it = 0; it < 2; ++it) {
            int fi = it * 256 + tid;
            int r = fi >> 2, cq = fi & 3;
            float4 v = *(const float4*)(w_qkv + r*CH + cc + cq*4);
            rb.wsm[r][cq*4+0] = v.x;
            rb.wsm[r][cq*4+1] = v.y;
            rb.wsm[r][cq*4+2] = v.z;
            rb.wsm[r][cq*4+3] = v.w;
        }
        __syncthreads();
#pragma unroll
        for (int k = 0; k < 16; ++k) {
            float rw[4], xv[8];
#pragma unroll
            for (int i = 0; i < 4; ++i) rw[i] = rb.wsm[rt*4+i][k];
#pragma unroll
            for (int j = 0; j < 8; ++j) xv[j] = ra.xns[cc+k][nt*8+j];
#pragma unroll
            for (int i = 0; i < 4; ++i)
#pragma unroll
                for (int j = 0; j < 8; ++j) acc[i][j] += rw[i]*xv[j];
        }
    }
    __syncthreads();
#pragma unroll
    for (int i = 0; i < 4; ++i)
#pragma unroll
        for (int j = 0; j < 8; ++j) qs[rt*4+i][nt*8+j] = acc[i][j];
    for (int idx = tid; idx < 4096; idx += 256) {
        int e = idx & 31, dd = (idx >> 5) & 31, h2 = idx >> 10;
        rb.ctxs[h2][dd][e] = ctx[b*4096 + idx] / Z[b*128 + h2*32 + dd];
    }
    __syncthreads();

    {   // softmax over d per (h,n) column
        int h2 = tid >> 6, n = tid & 63;
        float pv[32]; float ssum = 0.f;
#pragma unroll
        for (int dd = 0; dd < 32; ++dd) { pv[dd] = expf(qs[h2*32+dd][n]); ssum += pv[dd]; }
        float inv = SCALE / ssum;
#pragma unroll
        for (int dd = 0; dd < 32; ++dd) qs[h2*32+dd][n] = pv[dd] * inv;
    }
    __syncthreads();

    {   // hid[e][n] = sum_d ctx[d][e] * qprob[d][n]   (per head)
        int h2 = tid >> 6, l = tid & 63;
        int et = l >> 3, nt2 = l & 7;
        float a3[4][8];
#pragma unroll
        for (int i = 0; i < 4; ++i)
#pragma unroll
            for (int j = 0; j < 8; ++j) a3[i][j] = 0.f;
#pragma unroll
        for (int dd = 0; dd < 32; ++dd) {
            float4 cv = *(const float4*)&rb.ctxs[h2][dd][et*4];
            float rw[4] = {cv.x, cv.y, cv.z, cv.w};
            float xv[8];
#pragma unroll
            for (int j = 0; j < 8; ++j) xv[j] = qs[h2*32+dd][nt2*8+j];
#pragma unroll
            for (int i = 0; i < 4; ++i)
#pragma unroll
                for (int j = 0; j < 8; ++j) a3[i][j] += rw[i]*xv[j];
        }
#pragma unroll
        for (int i = 0; i < 4; ++i)
#pragma unroll
            for (int j = 0; j < 8; ++j) ra.hid[h2*32 + et*4 + i][nt2*8 + j] = a3[i][j];
    }

    float a2[4][8];
#pragma unroll
    for (int i = 0; i < 4; ++i)
#pragma unroll
        for (int j = 0; j < 8; ++j) a2[i][j] = 0.f;
    for (int cc = 0; cc < 128; cc += 16) {     // final GEMM: w_out @ hid
        __syncthreads();
#pragma unroll
        for (int it = 0; it < 2; ++it) {
            int fi = it * 256 + tid;
            int r = fi >> 2, cq = fi & 3;
            float4 v = *(const float4*)(w_out + r*CH + cc + cq*4);
            rb.wsm[r][cq*4+0] = v.x;
            rb.wsm[r][cq*4+1] = v.y;
            rb.wsm[r][cq*4+2] = v.z;
            rb.wsm[r][cq*4+3] = v.w;
        }
        __syncthreads();
#pragma unroll
        for (int k = 0; k < 16; ++k) {
            float rw[4], hv[8];
#pragma unroll
            for (int i = 0; i < 4; ++i) rw[i] = rb.wsm[rt*4+i][k];
#pragma unroll
            for (int j = 0; j < 8; ++j) hv[j] = ra.hid[cc+k][nt*8+j];
#pragma unroll
            for (int i = 0; i < 4; ++i)
#pragma unroll
                for (int j = 0; j < 8; ++j) a2[i][j] += rw[i]*hv[j];
        }
    }

    float gs = 0.f, gq = 0.f;
#pragma unroll
    for (int i = 0; i < 4; ++i) {
        int c = rt*4 + i;
        float bo = b_out[c];
        float o[8];
#pragma unroll
        for (int j = 0; j < 8; ++j) { o[j] = a2[i][j] + bo; gs += o[j]; gq += o[j]*o[j]; }
        float* dst = out + ((b*CH + c) << 16) + n0 + nt*8;
        *(float4*)dst       = make_float4(o[0], o[1], o[2], o[3]);
        *(float4*)(dst + 4) = make_float4(o[4], o[5], o[6], o[7]);
    }
    // gn2 partial: reduce over the 8 nt threads of each rt (group = rt)
    float2* rbuf = (float2*)&qs[0][0];
    rbuf[rt*8 + nt] = make_float2(gs, gq);
    __syncthreads();
    if (tid < 32) {
        float ss = 0.f, qq = 0.f;
#pragma unroll
        for (int k2 = 0; k2 < 8; ++k2) { float2 v = rbuf[tid*8 + k2]; ss += v.x; qq += v.y; }
        part2[blockIdx.x*64 + tid*2 + 0] = ss;
        part2[blockIdx.x*64 + tid*2 + 1] = qq;
    }
}

// ---------------- gn2 finalize --------------------------------------------------------
__global__ __launch_bounds__(256) void reduce2(const float* __restrict__ part2,
                                               float* __restrict__ mu, float* __restrict__ rs) {
    __shared__ float s1[256], s2[256];
    int fg = blockIdx.x;          // 0..63
    int b = fg >> 5, g = fg & 31;
    int t = threadIdx.x;
    float s = 0.f, q = 0.f;
    for (int i = t; i < 1024; i += 256) {
        const float* p = part2 + (size_t)(b*1024 + i)*64 + g*2;
        s += p[0]; q += p[1];
    }
    s1[t] = s; s2[t] = q;
    __syncthreads();
    for (int st = 128; st > 0; st >>= 1) {
        if (t < st) { s1[t] += s1[t + st]; s2[t] += s2[t + st]; }
        __syncthreads();
    }
    if (t == 0) {
        float m = s1[0] * (1.f / GSIZE);
        float v = s2[0] * (1.f / GSIZE) - m*m;
        mu[fg] = m; rs[fg] = rsqrtf(v + EPSV);
    }
}

__global__ __launch_bounds__(256) void gn_apply(float* __restrict__ y,
        const float* __restrict__ mu, const float* __restrict__ rs,
        const float* __restrict__ w2, const float* __restrict__ b2) {
    int bi = blockIdx.x, t = threadIdx.x;
    int c = (bi >> 3) & 127;
    int b = bi >> 10;
    int fg = b*32 + (c >> 2);
    float aa = rs[fg] * w2[c];
    float bb = b2[c] - mu[fg] * aa;
    float4* yp = (float4*)(y + (size_t)bi * 8192);
#pragma unroll
    for (int i = 0; i < 8; ++i) {
        float4 v = yp[t + 256*i];
        v.x = v.x*aa+bb; v.y = v.y*aa+bb; v.z = v.z*aa+bb; v.w = v.w*aa+bb;
        yp[t + 256*i] = v;
    }
}

extern "C" void kernel_launch(void* const* d_in, const int* in_sizes, int n_in,
                              void* d_out, int out_size, void* d_ws, size_t ws_size,
                              hipStream_t stream) {
    (void)in_sizes; (void)n_in; (void)out_size; (void)ws_size;
    const float* x      = (const float*)d_in[0];
    const float* n1w    = (const float*)d_in[1];
    const float* n1b    = (const float*)d_in[2];
    const float* w_qkv  = (const float*)d_in[3];
    const float* mem_kv = (const float*)d_in[4];
    const float* w_out  = (const float*)d_in[5];
    const float* b_out  = (const float*)d_in[6];
    const float* n2w    = (const float*)d_in[7];
    const float* n2b    = (const float*)d_in[8];
    float* out = (float*)d_out;
    float* ws  = (float*)d_ws;

    float* part1   = ws;              // 4096
    float* mu1     = ws + 4096;       // 64
    float* rs1     = ws + 4160;       // 64
    float* ctx     = ws + 4224;       // 8192
    float* Z       = ws + 12416;      // 256
    float* part2   = ws + 12672;      // 2048*64 = 131072
    float* mu2     = ws + 143744;     // 64
    float* rs2     = ws + 143808;     // 64
    float* part_kv = ws + 143872;     // 512*4224 = 2162688  (total ~9.2 MB)

    gn_partial<<<2048, 256, 0, stream>>>(x, part1);
    prep1<<<1, 64, 0, stream>>>(part1, mu1, rs1);
    kv_pass<<<512, 256, 0, stream>>>(x, w_qkv, n1w, n1b, mu1, rs1, part_kv);
    reduce_ctx<<<33, 256, 0, stream>>>(part_kv, mem_kv, ctx, Z);
    out_pass<<<2048, 256, 0, stream>>>(x, w_qkv, n1w, n1b, mu1, rs1, ctx, Z, w_out, b_out, out, part2);
    reduce2<<<64, 256, 0, stream>>>(part2, mu2, rs2);
    gn_apply<<<2048, 256, 0, stream>>>(out, mu2, rs2, n2w, n2b);
}

// Round 6
// 328.975 us; speedup vs baseline: 1.6107x; 1.6046x over previous
//
#include <hip/hip_runtime.h>
#include <math.h>

#define CH     128
#define EPSV   1e-5f
#define SCALE  0.17677669529663687f   // 32^-0.5
#define GSIZE  262144.0f

typedef short bf16x8 __attribute__((ext_vector_type(8)));
typedef float f32x4  __attribute__((ext_vector_type(4)));

__device__ __forceinline__ unsigned short f2bf(float f) {
    unsigned u = __float_as_uint(f);
    u += 0x7FFF + ((u >> 16) & 1);          // RNE
    return (unsigned short)(u >> 16);
}
__device__ __forceinline__ float bf2f(short s) {
    return __uint_as_float(((unsigned)(unsigned short)s) << 16);
}

// ---------------- group-norm partial stats (2048 blocks x 8192 elems) ----------------
__global__ __launch_bounds__(256) void gn_partial(const float* __restrict__ x,
                                                  float* __restrict__ part) {
    __shared__ float s1[256], s2[256];
    int t = threadIdx.x;
    const float4* xp = (const float4*)(x + (size_t)blockIdx.x * 8192);
    float s = 0.f, q = 0.f;
#pragma unroll
    for (int i = 0; i < 8; ++i) {
        float4 v = xp[t + 256 * i];
        s += v.x + v.y + v.z + v.w;
        q += v.x * v.x + v.y * v.y + v.z * v.z + v.w * v.w;
    }
    s1[t] = s; s2[t] = q;
    __syncthreads();
    for (int st = 128; st > 0; st >>= 1) {
        if (t < st) { s1[t] += s1[t + st]; s2[t] += s2[t + st]; }
        __syncthreads();
    }
    if (t == 0) { part[2 * blockIdx.x] = s1[0]; part[2 * blockIdx.x + 1] = s2[0]; }
}

// ---------------- finalize gn1 stats ---------------------------------------------------
__global__ void prep1(const float* __restrict__ part, float* __restrict__ mu, float* __restrict__ rs) {
    int t = threadIdx.x;   // 64 threads
    float s = 0.f, q = 0.f;
    for (int i = 0; i < 32; ++i) { s += part[2*(t*32+i)]; q += part[2*(t*32+i)+1]; }
    float m = s * (1.f / GSIZE);
    float v = q * (1.f / GSIZE) - m * m;
    mu[t] = m; rs[t] = rsqrtf(v + EPSV);
}

// ---------------- k/v pass (MFMA): K,V = Wkv@Xn ; ctx = exp(K)@V^T ; partials out ------
// grid 512 x 256thr (4 waves). Block bi: tiles bi*4..bi*4+3 (64 pos), batch bi>>8.
// Wave w: kv-GEMM rows 64w..64w+63 (waves 0-1 = K -> exp, 2-3 = V); ctx head h = w.
// NOTE: no min-occupancy arg in __launch_bounds__ (R2-R4: VGPR caps -> spills).
__global__ __launch_bounds__(256) void kv_pass(const float* __restrict__ x,
        const float* __restrict__ w_qkv,
        const float* __restrict__ n1w, const float* __restrict__ n1b,
        const float* __restrict__ mu, const float* __restrict__ rs,
        float* __restrict__ part_kv) {
    __shared__ short xk[16*64*8];        // bf16 [ch>>3][n][ch&7]  (16 KB)
    __shared__ short kvstage[8*256*8];   // bf16 [n>>3][row][n&7], bytes^((row>>2)&3)<<4 (32 KB)
    int tid = threadIdx.x;
    int l = tid & 63, w = tid >> 6;
    int ncol = l & 15, kg = l >> 4;
    int b = blockIdx.x >> 8;
    int h = w;

    // ---- persistent A-fragments: W k/v rows (bf16), loaded once ----
    bf16x8 afrag[4][4];                  // [row-tile][k-step]
    {
        int row0 = 128 + w*64 + ncol;
        int k0   = 8 * kg;
#pragma unroll
        for (int rt = 0; rt < 4; ++rt)
#pragma unroll
        for (int ks = 0; ks < 4; ++ks) {
            const float* p = w_qkv + (size_t)(row0 + 16*rt)*CH + k0 + 32*ks;
            float4 u0 = *(const float4*)p;
            float4 u1 = *(const float4*)(p + 4);
            bf16x8 f;
            f[0]=(short)f2bf(u0.x); f[1]=(short)f2bf(u0.y); f[2]=(short)f2bf(u0.z); f[3]=(short)f2bf(u0.w);
            f[4]=(short)f2bf(u1.x); f[5]=(short)f2bf(u1.y); f[6]=(short)f2bf(u1.z); f[7]=(short)f2bf(u1.w);
            afrag[rt][ks] = f;
        }
    }

    // ---- persistent GN scale/shift for this thread's 8 staging channels ----
    int nst = (tid & 15) * 4;            // 4 positions
    int cst = (tid >> 4) * 8;            // 8-channel octet
    float aa[8], bb[8];
#pragma unroll
    for (int i = 0; i < 8; ++i) {
        int c = cst + i;
        int fg = b*32 + (c >> 2);
        float a0 = rs[fg] * n1w[c];
        aa[i] = a0;
        bb[i] = n1b[c] - mu[fg] * a0;
    }

    f32x4 cc[2][2];                      // ctx accumulator (head h), persists across tiles
#pragma unroll
    for (int i = 0; i < 2; ++i)
#pragma unroll
    for (int j = 0; j < 2; ++j)
#pragma unroll
    for (int q = 0; q < 4; ++q) cc[i][j][q] = 0.f;
    float zacc = 0.f;

    for (int t4 = 0; t4 < 4; ++t4) {
        int n0 = ((blockIdx.x * 4 + t4) << 6) & 65535;

        // ---- stage x tile -> bf16 xk ----
        float4 xv[8];
#pragma unroll
        for (int i = 0; i < 8; ++i)
            xv[i] = *(const float4*)(x + ((size_t)(b*CH + cst + i) << 16) + n0 + nst);
        const float* xf = (const float*)xv;
#pragma unroll
        for (int j = 0; j < 4; ++j) {
            bf16x8 f;
#pragma unroll
            for (int i = 0; i < 8; ++i)
                f[i] = (short)f2bf(xf[i*4 + j] * aa[i] + bb[i]);
            *(bf16x8*)&xk[((cst >> 3)*64 + nst + j) * 8] = f;
        }
        __syncthreads();

        // ---- kv GEMM: 64 MFMA / wave ----
        f32x4 acc[4][4];
#pragma unroll
        for (int i = 0; i < 4; ++i)
#pragma unroll
        for (int j = 0; j < 4; ++j)
#pragma unroll
        for (int q = 0; q < 4; ++q) acc[i][j][q] = 0.f;

#pragma unroll
        for (int ks = 0; ks < 4; ++ks) {
            bf16x8 bfr[4];
#pragma unroll
            for (int ct = 0; ct < 4; ++ct)
                bfr[ct] = *(bf16x8*)&xk[((4*ks + kg)*64 + 16*ct + ncol) * 8];
#pragma unroll
            for (int rt = 0; rt < 4; ++rt)
#pragma unroll
            for (int ct = 0; ct < 4; ++ct)
                acc[rt][ct] = __builtin_amdgcn_mfma_f32_16x16x32_bf16(
                    afrag[rt][ks], bfr[ct], acc[rt][ct], 0, 0, 0);
        }

        // ---- exp(K)/V -> kvstage (bf16, swizzled). C layout: col=l&15, row=4*(l>>4)+reg
#pragma unroll
        for (int rt = 0; rt < 4; ++rt)
#pragma unroll
        for (int ct = 0; ct < 4; ++ct)
#pragma unroll
        for (int q = 0; q < 4; ++q) {
            float v = acc[rt][ct][q];
            if (w < 2) v = expf(v);
            int row = w*64 + 16*rt + 4*kg + q;
            int n   = 16*ct + ncol;
            int byteoff = ((n >> 3)*4096 + row*16 + (n & 7)*2) ^ (((row >> 2) & 3) << 4);
            *(short*)((char*)kvstage + byteoff) = (short)f2bf(v);
        }
        __syncthreads();

        // ---- ctx MFMA: head h, ctx += expK(32x64) @ V^T(64x32) ----
#pragma unroll
        for (int ks = 0; ks < 2; ++ks) {
            bf16x8 ak[2], bv[2];
#pragma unroll
            for (int rt = 0; rt < 2; ++rt) {
                int row = h*32 + 16*rt + ncol;
                int byteoff = ((4*ks + kg)*4096 + row*16) ^ (((row >> 2) & 3) << 4);
                ak[rt] = *(bf16x8*)((char*)kvstage + byteoff);
            }
#pragma unroll
            for (int ct = 0; ct < 2; ++ct) {
                int row = 128 + h*32 + 16*ct + ncol;
                int byteoff = ((4*ks + kg)*4096 + row*16) ^ (((row >> 2) & 3) << 4);
                bv[ct] = *(bf16x8*)((char*)kvstage + byteoff);
            }
#pragma unroll
            for (int rt = 0; rt < 2; ++rt)
#pragma unroll
            for (int ct = 0; ct < 2; ++ct)
                cc[rt][ct] = __builtin_amdgcn_mfma_f32_16x16x32_bf16(
                    ak[rt], bv[ct], cc[rt][ct], 0, 0, 0);
        }
        // ---- Z partial: lane (d=l&31, half=l>>5) sums expK row over 32 n ----
        {
            int d = l & 31, nh = l >> 5;
            int row = h*32 + d;
#pragma unroll
            for (int q = 0; q < 4; ++q) {
                int byteoff = (((nh*4 + q)*4096) + row*16) ^ (((row >> 2) & 3) << 4);
                bf16x8 e8 = *(bf16x8*)((char*)kvstage + byteoff);
#pragma unroll
                for (int j = 0; j < 8; ++j) zacc += bf2f(e8[j]);
            }
        }
        __syncthreads();
    }

    // ---- streaming partial write ----
    float* dst = part_kv + (size_t)blockIdx.x * 4224;
#pragma unroll
    for (int rt = 0; rt < 2; ++rt)
#pragma unroll
    for (int ct = 0; ct < 2; ++ct)
#pragma unroll
    for (int q = 0; q < 4; ++q) {
        int d = 16*rt + 4*kg + q;
        int e = 16*ct + ncol;
        dst[h*1024 + d*32 + e] = cc[rt][ct][q];
    }
    float zs = zacc + __shfl_down(zacc, 32);
    if (l < 32) dst[4096 + h*32 + l] = zs;
}

// ---------------- reduce partials + memory-kv init -> ctx, Z ---------------------------
__global__ void reduce_ctx(const float* __restrict__ part_kv, const float* __restrict__ mem_kv,
                           float* __restrict__ ctx, float* __restrict__ Z) {
    int gid = blockIdx.x * 256 + threadIdx.x;   // 0..8447
    int b = gid / 4224;
    int e = gid - b * 4224;
    const float* p = part_kv + (size_t)b * 256 * 4224 + e;
    float s0 = 0.f, s1 = 0.f, s2 = 0.f, s3 = 0.f;
    for (int i = 0; i < 256; i += 4) {
        s0 += p[(i+0)*4224];
        s1 += p[(i+1)*4224];
        s2 += p[(i+2)*4224];
        s3 += p[(i+3)*4224];
    }
    float s = (s0 + s1) + (s2 + s3);
    if (e < 4096) {
        int hh = e >> 10, d = (e >> 5) & 31, ee = e & 31;
        float init = 0.f;
        for (int m = 0; m < 4; ++m)
            init += expf(mem_kv[hh*128 + d*4 + m]) * mem_kv[512 + hh*128 + ee*4 + m];
        ctx[b*4096 + e] = init + s;
    } else {
        int d2 = e - 4096;
        float init = 0.f;
        for (int m = 0; m < 4; ++m) init += expf(mem_kv[d2*4 + m]);
        Z[b*128 + d2] = init + s;
    }
}

// ---------------- out pass: q GEMM -> softmax(d) -> ctx apply -> w_out GEMM + gn2 part --
__global__ __launch_bounds__(256, 2) void out_pass(const float* __restrict__ x,
        const float* __restrict__ w_qkv,
        const float* __restrict__ n1w, const float* __restrict__ n1b,
        const float* __restrict__ mu, const float* __restrict__ rs,
        const float* __restrict__ ctx, const float* __restrict__ Z,
        const float* __restrict__ w_out, const float* __restrict__ b_out,
        float* __restrict__ out, float* __restrict__ part2) {
    __shared__ union { float xns[128][64]; float hid[128][64]; } ra;
    __shared__ union { float wsm[128][17]; float ctxs[4][32][32]; } rb;
    __shared__ float qs[128][64];
    int tid = threadIdx.x;
    int p0 = blockIdx.x << 6;
    int b  = p0 >> 16;
    int n0 = p0 & 65535;

#pragma unroll
    for (int it = 0; it < 8; ++it) {
        int fi = it * 256 + tid;
        int c = fi >> 4, nq = fi & 15;
        float4 v = *(const float4*)(x + ((b*CH + c) << 16) + n0 + nq*4);
        int fg = b*32 + (c >> 2);
        float aa = rs[fg] * n1w[c];
        float bb = n1b[c] - mu[fg] * aa;
        ra.xns[c][nq*4+0] = v.x*aa+bb;
        ra.xns[c][nq*4+1] = v.y*aa+bb;
        ra.xns[c][nq*4+2] = v.z*aa+bb;
        ra.xns[c][nq*4+3] = v.w*aa+bb;
    }

    float acc[4][8];
#pragma unroll
    for (int i = 0; i < 4; ++i)
#pragma unroll
        for (int j = 0; j < 8; ++j) acc[i][j] = 0.f;
    int rt = tid >> 3, nt = tid & 7;
    for (int cc = 0; cc < 128; cc += 16) {    // q GEMM: w_qkv rows 0..127
        __syncthreads();
#pragma unroll
        for (int it = 0; it < 2; ++it) {
            int fi = it * 256 + tid;
            int r = fi >> 2, cq = fi & 3;
            float4 v = *(const float4*)(w_qkv + r*CH + cc + cq*4);
            rb.wsm[r][cq*4+0] = v.x;
            rb.wsm[r][cq*4+1] = v.y;
            rb.wsm[r][cq*4+2] = v.z;
            rb.wsm[r][cq*4+3] = v.w;
        }
        __syncthreads();
#pragma unroll
        for (int k = 0; k < 16; ++k) {
            float rw[4], xv[8];
#pragma unroll
            for (int i = 0; i < 4; ++i) rw[i] = rb.wsm[rt*4+i][k];
#pragma unroll
            for (int j = 0; j < 8; ++j) xv[j] = ra.xns[cc+k][nt*8+j];
#pragma unroll
            for (int i = 0; i < 4; ++i)
#pragma unroll
                for (int j = 0; j < 8; ++j) acc[i][j] += rw[i]*xv[j];
        }
    }
    __syncthreads();
#pragma unroll
    for (int i = 0; i < 4; ++i)
#pragma unroll
        for (int j = 0; j < 8; ++j) qs[rt*4+i][nt*8+j] = acc[i][j];
    for (int idx = tid; idx < 4096; idx += 256) {
        int e = idx & 31, dd = (idx >> 5) & 31, h2 = idx >> 10;
        rb.ctxs[h2][dd][e] = ctx[b*4096 + idx] / Z[b*128 + h2*32 + dd];
    }
    __syncthreads();

    {   // softmax over d per (h,n) column
        int h2 = tid >> 6, n = tid & 63;
        float pv[32]; float ssum = 0.f;
#pragma unroll
        for (int dd = 0; dd < 32; ++dd) { pv[dd] = expf(qs[h2*32+dd][n]); ssum += pv[dd]; }
        float inv = SCALE / ssum;
#pragma unroll
        for (int dd = 0; dd < 32; ++dd) qs[h2*32+dd][n] = pv[dd] * inv;
    }
    __syncthreads();

    {   // hid[e][n] = sum_d ctx[d][e] * qprob[d][n]   (per head)
        int h2 = tid >> 6, l = tid & 63;
        int et = l >> 3, nt2 = l & 7;
        float a3[4][8];
#pragma unroll
        for (int i = 0; i < 4; ++i)
#pragma unroll
            for (int j = 0; j < 8; ++j) a3[i][j] = 0.f;
#pragma unroll
        for (int dd = 0; dd < 32; ++dd) {
            float4 cv = *(const float4*)&rb.ctxs[h2][dd][et*4];
            float rw[4] = {cv.x, cv.y, cv.z, cv.w};
            float xv[8];
#pragma unroll
            for (int j = 0; j < 8; ++j) xv[j] = qs[h2*32+dd][nt2*8+j];
#pragma unroll
            for (int i = 0; i < 4; ++i)
#pragma unroll
                for (int j = 0; j < 8; ++j) a3[i][j] += rw[i]*xv[j];
        }
#pragma unroll
        for (int i = 0; i < 4; ++i)
#pragma unroll
            for (int j = 0; j < 8; ++j) ra.hid[h2*32 + et*4 + i][nt2*8 + j] = a3[i][j];
    }

    float a2[4][8];
#pragma unroll
    for (int i = 0; i < 4; ++i)
#pragma unroll
        for (int j = 0; j < 8; ++j) a2[i][j] = 0.f;
    for (int cc = 0; cc < 128; cc += 16) {     // final GEMM: w_out @ hid
        __syncthreads();
#pragma unroll
        for (int it = 0; it < 2; ++it) {
            int fi = it * 256 + tid;
            int r = fi >> 2, cq = fi & 3;
            float4 v = *(const float4*)(w_out + r*CH + cc + cq*4);
            rb.wsm[r][cq*4+0] = v.x;
            rb.wsm[r][cq*4+1] = v.y;
            rb.wsm[r][cq*4+2] = v.z;
            rb.wsm[r][cq*4+3] = v.w;
        }
        __syncthreads();
#pragma unroll
        for (int k = 0; k < 16; ++k) {
            float rw[4], hv[8];
#pragma unroll
            for (int i = 0; i < 4; ++i) rw[i] = rb.wsm[rt*4+i][k];
#pragma unroll
            for (int j = 0; j < 8; ++j) hv[j] = ra.hid[cc+k][nt*8+j];
#pragma unroll
            for (int i = 0; i < 4; ++i)
#pragma unroll
                for (int j = 0; j < 8; ++j) a2[i][j] += rw[i]*hv[j];
        }
    }

    float gs = 0.f, gq = 0.f;
#pragma unroll
    for (int i = 0; i < 4; ++i) {
        int c = rt*4 + i;
        float bo = b_out[c];
        float o[8];
#pragma unroll
        for (int j = 0; j < 8; ++j) { o[j] = a2[i][j] + bo; gs += o[j]; gq += o[j]*o[j]; }
        float* dst = out + ((b*CH + c) << 16) + n0 + nt*8;
        *(float4*)dst       = make_float4(o[0], o[1], o[2], o[3]);
        *(float4*)(dst + 4) = make_float4(o[4], o[5], o[6], o[7]);
    }
    // gn2 partial: reduce over the 8 nt threads of each rt (group = rt)
    float2* rbuf = (float2*)&qs[0][0];
    rbuf[rt*8 + nt] = make_float2(gs, gq);
    __syncthreads();
    if (tid < 32) {
        float ss = 0.f, qq = 0.f;
#pragma unroll
        for (int k2 = 0; k2 < 8; ++k2) { float2 v = rbuf[tid*8 + k2]; ss += v.x; qq += v.y; }
        part2[blockIdx.x*64 + tid*2 + 0] = ss;
        part2[blockIdx.x*64 + tid*2 + 1] = qq;
    }
}

// ---------------- gn2 finalize --------------------------------------------------------
__global__ __launch_bounds__(256) void reduce2(const float* __restrict__ part2,
                                               float* __restrict__ mu, float* __restrict__ rs) {
    __shared__ float s1[256], s2[256];
    int fg = blockIdx.x;          // 0..63
    int b = fg >> 5, g = fg & 31;
    int t = threadIdx.x;
    float s = 0.f, q = 0.f;
    for (int i = t; i < 1024; i += 256) {
        const float* p = part2 + (size_t)(b*1024 + i)*64 + g*2;
        s += p[0]; q += p[1];
    }
    s1[t] = s; s2[t] = q;
    __syncthreads();
    for (int st = 128; st > 0; st >>= 1) {
        if (t < st) { s1[t] += s1[t + st]; s2[t] += s2[t + st]; }
        __syncthreads();
    }
    if (t == 0) {
        float m = s1[0] * (1.f / GSIZE);
        float v = s2[0] * (1.f / GSIZE) - m*m;
        mu[fg] = m; rs[fg] = rsqrtf(v + EPSV);
    }
}

__global__ __launch_bounds__(256) void gn_apply(float* __restrict__ y,
        const float* __restrict__ mu, const float* __restrict__ rs,
        const float* __restrict__ w2, const float* __restrict__ b2) {
    int bi = blockIdx.x, t = threadIdx.x;
    int c = (bi >> 3) & 127;
    int b = bi >> 10;
    int fg = b*32 + (c >> 2);
    float aa = rs[fg] * w2[c];
    float bb = b2[c] - mu[fg] * aa;
    float4* yp = (float4*)(y + (size_t)bi * 8192);
#pragma unroll
    for (int i = 0; i < 8; ++i) {
        float4 v = yp[t + 256*i];
        v.x = v.x*aa+bb; v.y = v.y*aa+bb; v.z = v.z*aa+bb; v.w = v.w*aa+bb;
        yp[t + 256*i] = v;
    }
}

extern "C" void kernel_launch(void* const* d_in, const int* in_sizes, int n_in,
                              void* d_out, int out_size, void* d_ws, size_t ws_size,
                              hipStream_t stream) {
    (void)in_sizes; (void)n_in; (void)out_size; (void)ws_size;
    const float* x      = (const float*)d_in[0];
    const float* n1w    = (const float*)d_in[1];
    const float* n1b    = (const float*)d_in[2];
    const float* w_qkv  = (const float*)d_in[3];
    const float* mem_kv = (const float*)d_in[4];
    const float* w_out  = (const float*)d_in[5];
    const float* b_out  = (const float*)d_in[6];
    const float* n2w    = (const float*)d_in[7];
    const float* n2b    = (const float*)d_in[8];
    float* out = (float*)d_out;
    float* ws  = (float*)d_ws;

    float* part1   = ws;              // 4096
    float* mu1     = ws + 4096;       // 64
    float* rs1     = ws + 4160;       // 64
    float* ctx     = ws + 4224;       // 8192
    float* Z       = ws + 12416;      // 256
    float* part2   = ws + 12672;      // 2048*64 = 131072
    float* mu2     = ws + 143744;     // 64
    float* rs2     = ws + 143808;     // 64
    float* part_kv = ws + 143872;     // 512*4224 = 2162688  (total ~9.2 MB)

    gn_partial<<<2048, 256, 0, stream>>>(x, part1);
    prep1<<<1, 64, 0, stream>>>(part1, mu1, rs1);
    kv_pass<<<512, 256, 0, stream>>>(x, w_qkv, n1w, n1b, mu1, rs1, part_kv);
    reduce_ctx<<<33, 256, 0, stream>>>(part_kv, mem_kv, ctx, Z);
    out_pass<<<2048, 256, 0, stream>>>(x, w_qkv, n1w, n1b, mu1, rs1, ctx, Z, w_out, b_out, out, part2);
    reduce2<<<64, 256, 0, stream>>>(part2, mu2, rs2);
    gn_apply<<<2048, 256, 0, stream>>>(out, mu2, rs2, n2w, n2b);
}

// Round 7
// 163.201 us; speedup vs baseline: 3.2468x; 2.0158x over previous
//
#include <hip/hip_runtime.h>
#include <math.h>

#define CH     128
#define EPSV   1e-5f
#define SCALE  0.17677669529663687f   // 32^-0.5
#define GSIZE  262144.0f

typedef short bf16x8 __attribute__((ext_vector_type(8)));
typedef short bf16x4 __attribute__((ext_vector_type(4)));
typedef float f32x4  __attribute__((ext_vector_type(4)));

__device__ __forceinline__ unsigned short f2bf(float f) {
    unsigned u = __float_as_uint(f);
    u += 0x7FFF + ((u >> 16) & 1);          // RNE
    return (unsigned short)(u >> 16);
}
__device__ __forceinline__ float bf2f(short s) {
    return __uint_as_float(((unsigned)(unsigned short)s) << 16);
}

// ---------------- group-norm partial stats (2048 blocks x 8192 elems) ----------------
__global__ __launch_bounds__(256) void gn_partial(const float* __restrict__ x,
                                                  float* __restrict__ part) {
    __shared__ float s1[256], s2[256];
    int t = threadIdx.x;
    const float4* xp = (const float4*)(x + (size_t)blockIdx.x * 8192);
    float s = 0.f, q = 0.f;
#pragma unroll
    for (int i = 0; i < 8; ++i) {
        float4 v = xp[t + 256 * i];
        s += v.x + v.y + v.z + v.w;
        q += v.x * v.x + v.y * v.y + v.z * v.z + v.w * v.w;
    }
    s1[t] = s; s2[t] = q;
    __syncthreads();
    for (int st = 128; st > 0; st >>= 1) {
        if (t < st) { s1[t] += s1[t + st]; s2[t] += s2[t + st]; }
        __syncthreads();
    }
    if (t == 0) { part[2 * blockIdx.x] = s1[0]; part[2 * blockIdx.x + 1] = s2[0]; }
}

// ---------------- finalize gn1 stats ---------------------------------------------------
__global__ void prep1(const float* __restrict__ part, float* __restrict__ mu, float* __restrict__ rs) {
    int t = threadIdx.x;   // 64 threads
    float s = 0.f, q = 0.f;
    for (int i = 0; i < 32; ++i) { s += part[2*(t*32+i)]; q += part[2*(t*32+i)+1]; }
    float m = s * (1.f / GSIZE);
    float v = q * (1.f / GSIZE) - m * m;
    mu[t] = m; rs[t] = rsqrtf(v + EPSV);
}

// ---------------- k/v pass (MFMA): K,V = Wkv@Xn ; ctx = exp(K)@V^T ; partials out ------
// grid 512 x 256thr (4 waves). Block bi: tiles bi*4..bi*4+3 (64 pos), batch bi>>8.
// Wave w: kv-GEMM rows 64w..64w+63 (waves 0-1 = K -> exp, 2-3 = V); ctx head h = w.
// NOTE: no min-occupancy arg in __launch_bounds__ (R2-R4: VGPR caps -> spills).
__global__ __launch_bounds__(256) void kv_pass(const float* __restrict__ x,
        const float* __restrict__ w_qkv,
        const float* __restrict__ n1w, const float* __restrict__ n1b,
        const float* __restrict__ mu, const float* __restrict__ rs,
        float* __restrict__ part_kv) {
    __shared__ short xk[16*64*8];        // bf16 [ch>>3][n][ch&7]  (16 KB)
    __shared__ short kvstage[8*256*8];   // bf16 [n>>3][row][n&7], bytes^((row>>2)&3)<<4 (32 KB)
    int tid = threadIdx.x;
    int l = tid & 63, w = tid >> 6;
    int ncol = l & 15, kg = l >> 4;
    int b = blockIdx.x >> 8;
    int h = w;

    // ---- persistent A-fragments: W k/v rows (bf16), loaded once ----
    bf16x8 afrag[4][4];                  // [row-tile][k-step]
    {
        int row0 = 128 + w*64 + ncol;
        int k0   = 8 * kg;
#pragma unroll
        for (int rt = 0; rt < 4; ++rt)
#pragma unroll
        for (int ks = 0; ks < 4; ++ks) {
            const float* p = w_qkv + (size_t)(row0 + 16*rt)*CH + k0 + 32*ks;
            float4 u0 = *(const float4*)p;
            float4 u1 = *(const float4*)(p + 4);
            bf16x8 f;
            f[0]=(short)f2bf(u0.x); f[1]=(short)f2bf(u0.y); f[2]=(short)f2bf(u0.z); f[3]=(short)f2bf(u0.w);
            f[4]=(short)f2bf(u1.x); f[5]=(short)f2bf(u1.y); f[6]=(short)f2bf(u1.z); f[7]=(short)f2bf(u1.w);
            afrag[rt][ks] = f;
        }
    }

    // ---- persistent GN scale/shift for this thread's 8 staging channels ----
    int nst = (tid & 15) * 4;            // 4 positions
    int cst = (tid >> 4) * 8;            // 8-channel octet
    float aa[8], bb[8];
#pragma unroll
    for (int i = 0; i < 8; ++i) {
        int c = cst + i;
        int fg = b*32 + (c >> 2);
        float a0 = rs[fg] * n1w[c];
        aa[i] = a0;
        bb[i] = n1b[c] - mu[fg] * a0;
    }

    f32x4 cc[2][2];                      // ctx accumulator (head h), persists across tiles
#pragma unroll
    for (int i = 0; i < 2; ++i)
#pragma unroll
    for (int j = 0; j < 2; ++j)
#pragma unroll
    for (int q = 0; q < 4; ++q) cc[i][j][q] = 0.f;
    float zacc = 0.f;

    for (int t4 = 0; t4 < 4; ++t4) {
        int n0 = ((blockIdx.x * 4 + t4) << 6) & 65535;

        // ---- stage x tile -> bf16 xk ----
        float4 xv[8];
#pragma unroll
        for (int i = 0; i < 8; ++i)
            xv[i] = *(const float4*)(x + ((size_t)(b*CH + cst + i) << 16) + n0 + nst);
        const float* xf = (const float*)xv;
#pragma unroll
        for (int j = 0; j < 4; ++j) {
            bf16x8 f;
#pragma unroll
            for (int i = 0; i < 8; ++i)
                f[i] = (short)f2bf(xf[i*4 + j] * aa[i] + bb[i]);
            *(bf16x8*)&xk[((cst >> 3)*64 + nst + j) * 8] = f;
        }
        __syncthreads();

        // ---- kv GEMM: 64 MFMA / wave ----
        f32x4 acc[4][4];
#pragma unroll
        for (int i = 0; i < 4; ++i)
#pragma unroll
        for (int j = 0; j < 4; ++j)
#pragma unroll
        for (int q = 0; q < 4; ++q) acc[i][j][q] = 0.f;

#pragma unroll
        for (int ks = 0; ks < 4; ++ks) {
            bf16x8 bfr[4];
#pragma unroll
            for (int ct = 0; ct < 4; ++ct)
                bfr[ct] = *(bf16x8*)&xk[((4*ks + kg)*64 + 16*ct + ncol) * 8];
#pragma unroll
            for (int rt = 0; rt < 4; ++rt)
#pragma unroll
            for (int ct = 0; ct < 4; ++ct)
                acc[rt][ct] = __builtin_amdgcn_mfma_f32_16x16x32_bf16(
                    afrag[rt][ks], bfr[ct], acc[rt][ct], 0, 0, 0);
        }

        // ---- exp(K)/V -> kvstage (bf16, swizzled). C layout: col=l&15, row=4*(l>>4)+reg
#pragma unroll
        for (int rt = 0; rt < 4; ++rt)
#pragma unroll
        for (int ct = 0; ct < 4; ++ct)
#pragma unroll
        for (int q = 0; q < 4; ++q) {
            float v = acc[rt][ct][q];
            if (w < 2) v = expf(v);
            int row = w*64 + 16*rt + 4*kg + q;
            int n   = 16*ct + ncol;
            int byteoff = ((n >> 3)*4096 + row*16 + (n & 7)*2) ^ (((row >> 2) & 3) << 4);
            *(short*)((char*)kvstage + byteoff) = (short)f2bf(v);
        }
        __syncthreads();

        // ---- ctx MFMA: head h, ctx += expK(32x64) @ V^T(64x32) ----
#pragma unroll
        for (int ks = 0; ks < 2; ++ks) {
            bf16x8 ak[2], bv[2];
#pragma unroll
            for (int rt = 0; rt < 2; ++rt) {
                int row = h*32 + 16*rt + ncol;
                int byteoff = ((4*ks + kg)*4096 + row*16) ^ (((row >> 2) & 3) << 4);
                ak[rt] = *(bf16x8*)((char*)kvstage + byteoff);
            }
#pragma unroll
            for (int ct = 0; ct < 2; ++ct) {
                int row = 128 + h*32 + 16*ct + ncol;
                int byteoff = ((4*ks + kg)*4096 + row*16) ^ (((row >> 2) & 3) << 4);
                bv[ct] = *(bf16x8*)((char*)kvstage + byteoff);
            }
#pragma unroll
            for (int rt = 0; rt < 2; ++rt)
#pragma unroll
            for (int ct = 0; ct < 2; ++ct)
                cc[rt][ct] = __builtin_amdgcn_mfma_f32_16x16x32_bf16(
                    ak[rt], bv[ct], cc[rt][ct], 0, 0, 0);
        }
        // ---- Z partial: lane (d=l&31, half=l>>5) sums expK row over 32 n ----
        {
            int d = l & 31, nh = l >> 5;
            int row = h*32 + d;
#pragma unroll
            for (int q = 0; q < 4; ++q) {
                int byteoff = (((nh*4 + q)*4096) + row*16) ^ (((row >> 2) & 3) << 4);
                bf16x8 e8 = *(bf16x8*)((char*)kvstage + byteoff);
#pragma unroll
                for (int j = 0; j < 8; ++j) zacc += bf2f(e8[j]);
            }
        }
        __syncthreads();
    }

    // ---- streaming partial write ----
    float* dst = part_kv + (size_t)blockIdx.x * 4224;
#pragma unroll
    for (int rt = 0; rt < 2; ++rt)
#pragma unroll
    for (int ct = 0; ct < 2; ++ct)
#pragma unroll
    for (int q = 0; q < 4; ++q) {
        int d = 16*rt + 4*kg + q;
        int e = 16*ct + ncol;
        dst[h*1024 + d*32 + e] = cc[rt][ct][q];
    }
    float zs = zacc + __shfl_down(zacc, 32);
    if (l < 32) dst[4096 + h*32 + l] = zs;
}

// ---------------- reduce partials + memory-kv init -> ctx, Z ---------------------------
__global__ void reduce_ctx(const float* __restrict__ part_kv, const float* __restrict__ mem_kv,
                           float* __restrict__ ctx, float* __restrict__ Z) {
    int gid = blockIdx.x * 256 + threadIdx.x;   // 0..8447
    int b = gid / 4224;
    int e = gid - b * 4224;
    const float* p = part_kv + (size_t)b * 256 * 4224 + e;
    float s0 = 0.f, s1 = 0.f, s2 = 0.f, s3 = 0.f;
    for (int i = 0; i < 256; i += 4) {
        s0 += p[(i+0)*4224];
        s1 += p[(i+1)*4224];
        s2 += p[(i+2)*4224];
        s3 += p[(i+3)*4224];
    }
    float s = (s0 + s1) + (s2 + s3);
    if (e < 4096) {
        int hh = e >> 10, d = (e >> 5) & 31, ee = e & 31;
        float init = 0.f;
        for (int m = 0; m < 4; ++m)
            init += expf(mem_kv[hh*128 + d*4 + m]) * mem_kv[512 + hh*128 + ee*4 + m];
        ctx[b*4096 + e] = init + s;
    } else {
        int d2 = e - 4096;
        float init = 0.f;
        for (int m = 0; m < 4; ++m) init += expf(mem_kv[d2*4 + m]);
        Z[b*128 + d2] = init + s;
    }
}

// ---------------- out pass (MFMA): q GEMM -> softmax -> hid -> w_out GEMM + gn2 --------
// grid 512 x 256thr (4 waves). Block bi: tiles bi*4..bi*4+3 (64 pos), batch bi>>8.
// Wave w: head w for q/hid; output rows 32w..32w+31 for q and w_out GEMMs.
// One 16 KB LDS buffer cycles xn -> qprob -> hid between barriers.
// NOTE: no min-occupancy arg in __launch_bounds__ (R2-R4: VGPR caps -> spills).
__global__ __launch_bounds__(256) void out_pass(const float* __restrict__ x,
        const float* __restrict__ w_qkv,
        const float* __restrict__ n1w, const float* __restrict__ n1b,
        const float* __restrict__ mu, const float* __restrict__ rs,
        const float* __restrict__ ctx, const float* __restrict__ Z,
        const float* __restrict__ w_out, const float* __restrict__ b_out,
        float* __restrict__ out, float* __restrict__ part2) {
    __shared__ short xk[16*64*8];        // bf16 [row>>3][n][row&7]  (16 KB)
    int tid = threadIdx.x;
    int l = tid & 63, w = tid >> 6;
    int ncol = l & 15, kg = l >> 4;
    int b = blockIdx.x >> 8;

    // ---- persistent A-fragments: W_q and W_out rows 32w..32w+31 ----
    bf16x8 aq[2][4], aw[2][4];
#pragma unroll
    for (int rt = 0; rt < 2; ++rt)
#pragma unroll
    for (int ks = 0; ks < 4; ++ks) {
        const float* pq = w_qkv + (size_t)(32*w + 16*rt + ncol)*CH + 8*kg + 32*ks;
        const float* pw = w_out + (size_t)(32*w + 16*rt + ncol)*CH + 8*kg + 32*ks;
        float4 u0 = *(const float4*)pq, u1 = *(const float4*)(pq + 4);
        float4 v0 = *(const float4*)pw, v1 = *(const float4*)(pw + 4);
        bf16x8 fq, fw;
        fq[0]=(short)f2bf(u0.x); fq[1]=(short)f2bf(u0.y); fq[2]=(short)f2bf(u0.z); fq[3]=(short)f2bf(u0.w);
        fq[4]=(short)f2bf(u1.x); fq[5]=(short)f2bf(u1.y); fq[6]=(short)f2bf(u1.z); fq[7]=(short)f2bf(u1.w);
        fw[0]=(short)f2bf(v0.x); fw[1]=(short)f2bf(v0.y); fw[2]=(short)f2bf(v0.z); fw[3]=(short)f2bf(v0.w);
        fw[4]=(short)f2bf(v1.x); fw[5]=(short)f2bf(v1.y); fw[6]=(short)f2bf(v1.z); fw[7]=(short)f2bf(v1.w);
        aq[rt][ks] = fq;
        aw[rt][ks] = fw;
    }

    // ---- persistent A-frag: normalized ctx^T (row e, k=d) for head w ----
    bf16x8 actx[2];
#pragma unroll
    for (int rt = 0; rt < 2; ++rt) {
        bf16x8 f;
#pragma unroll
        for (int j = 0; j < 8; ++j) {
            int d = 8*kg + j;
            float cv = ctx[b*4096 + w*1024 + d*32 + 16*rt + ncol] / Z[b*128 + w*32 + d];
            f[j] = (short)f2bf(cv);
        }
        actx[rt] = f;
    }

    // ---- persistent epilogue bias ----
    float bo[2][4];
#pragma unroll
    for (int rt = 0; rt < 2; ++rt)
#pragma unroll
    for (int q = 0; q < 4; ++q)
        bo[rt][q] = b_out[32*w + 16*rt + 4*kg + q];

    // ---- persistent GN scale/shift for staging channels ----
    int nst = (tid & 15) * 4;
    int cst = (tid >> 4) * 8;
    float aa[8], bb[8];
#pragma unroll
    for (int i = 0; i < 8; ++i) {
        int c = cst + i;
        int fg = b*32 + (c >> 2);
        float a0 = rs[fg] * n1w[c];
        aa[i] = a0;
        bb[i] = n1b[c] - mu[fg] * a0;
    }

    float pgs[2] = {0.f, 0.f}, pgq[2] = {0.f, 0.f};   // gn2 partials

    for (int t4 = 0; t4 < 4; ++t4) {
        int n0 = ((blockIdx.x * 4 + t4) << 6) & 65535;

        // ---- stage x tile -> bf16 xk ----
        float4 xv[8];
#pragma unroll
        for (int i = 0; i < 8; ++i)
            xv[i] = *(const float4*)(x + ((size_t)(b*CH + cst + i) << 16) + n0 + nst);
        const float* xf = (const float*)xv;
#pragma unroll
        for (int j = 0; j < 4; ++j) {
            bf16x8 f;
#pragma unroll
            for (int i = 0; i < 8; ++i)
                f[i] = (short)f2bf(xf[i*4 + j] * aa[i] + bb[i]);
            *(bf16x8*)&xk[((cst >> 3)*64 + nst + j) * 8] = f;
        }
        __syncthreads();

        // ---- q GEMM: 32 MFMA / wave ----
        f32x4 acc[2][4];
#pragma unroll
        for (int i = 0; i < 2; ++i)
#pragma unroll
        for (int j = 0; j < 4; ++j)
#pragma unroll
        for (int q = 0; q < 4; ++q) acc[i][j][q] = 0.f;
#pragma unroll
        for (int ks = 0; ks < 4; ++ks) {
            bf16x8 bfr[4];
#pragma unroll
            for (int ct = 0; ct < 4; ++ct)
                bfr[ct] = *(bf16x8*)&xk[((4*ks + kg)*64 + 16*ct + ncol) * 8];
#pragma unroll
            for (int rt = 0; rt < 2; ++rt)
#pragma unroll
            for (int ct = 0; ct < 4; ++ct)
                acc[rt][ct] = __builtin_amdgcn_mfma_f32_16x16x32_bf16(
                    aq[rt][ks], bfr[ct], acc[rt][ct], 0, 0, 0);
        }
        __syncthreads();                 // xk reads done before overwrite

        // ---- softmax over d (32 per head) for each column n; write qprob -> xk ----
        {
            float sum[4];
#pragma unroll
            for (int ct = 0; ct < 4; ++ct) {
                float s = 0.f;
#pragma unroll
                for (int rt = 0; rt < 2; ++rt)
#pragma unroll
                for (int q = 0; q < 4; ++q) {
                    float e = expf(acc[rt][ct][q]);
                    acc[rt][ct][q] = e;
                    s += e;
                }
                s += __shfl_xor(s, 16);
                s += __shfl_xor(s, 32);
                sum[ct] = SCALE / s;
            }
#pragma unroll
            for (int ct = 0; ct < 4; ++ct)
#pragma unroll
            for (int rt = 0; rt < 2; ++rt) {
                bf16x4 pk;
#pragma unroll
                for (int q = 0; q < 4; ++q) pk[q] = (short)f2bf(acc[rt][ct][q] * sum[ct]);
                int row0 = w*32 + 16*rt + 4*kg;        // row = head-base + d
                *(bf16x4*)&xk[((row0 >> 3)*64 + 16*ct + ncol)*8 + (row0 & 7)] = pk;
            }
        }
        __syncthreads();

        // ---- hid GEMM: hid[e][n] = ctx^T @ qprob (K=32, 8 MFMA / wave) ----
        f32x4 hacc[2][4];
#pragma unroll
        for (int i = 0; i < 2; ++i)
#pragma unroll
        for (int j = 0; j < 4; ++j)
#pragma unroll
        for (int q = 0; q < 4; ++q) hacc[i][j][q] = 0.f;
        {
            bf16x8 bq[4];
#pragma unroll
            for (int ct = 0; ct < 4; ++ct)
                bq[ct] = *(bf16x8*)&xk[((w*4 + kg)*64 + 16*ct + ncol) * 8];
#pragma unroll
            for (int rt = 0; rt < 2; ++rt)
#pragma unroll
            for (int ct = 0; ct < 4; ++ct)
                hacc[rt][ct] = __builtin_amdgcn_mfma_f32_16x16x32_bf16(
                    actx[rt], bq[ct], hacc[rt][ct], 0, 0, 0);
        }
        __syncthreads();                 // qprob reads done before overwrite

        // ---- write hid -> xk (rows = h*32 + e) ----
#pragma unroll
        for (int ct = 0; ct < 4; ++ct)
#pragma unroll
        for (int rt = 0; rt < 2; ++rt) {
            bf16x4 pk;
#pragma unroll
            for (int q = 0; q < 4; ++q) pk[q] = (short)f2bf(hacc[rt][ct][q]);
            int row0 = w*32 + 16*rt + 4*kg;
            *(bf16x4*)&xk[((row0 >> 3)*64 + 16*ct + ncol)*8 + (row0 & 7)] = pk;
        }
        __syncthreads();

        // ---- w_out GEMM: 32 MFMA / wave ----
        f32x4 oacc[2][4];
#pragma unroll
        for (int i = 0; i < 2; ++i)
#pragma unroll
        for (int j = 0; j < 4; ++j)
#pragma unroll
        for (int q = 0; q < 4; ++q) oacc[i][j][q] = 0.f;
#pragma unroll
        for (int ks = 0; ks < 4; ++ks) {
            bf16x8 bfr[4];
#pragma unroll
            for (int ct = 0; ct < 4; ++ct)
                bfr[ct] = *(bf16x8*)&xk[((4*ks + kg)*64 + 16*ct + ncol) * 8];
#pragma unroll
            for (int rt = 0; rt < 2; ++rt)
#pragma unroll
            for (int ct = 0; ct < 4; ++ct)
                oacc[rt][ct] = __builtin_amdgcn_mfma_f32_16x16x32_bf16(
                    aw[rt][ks], bfr[ct], oacc[rt][ct], 0, 0, 0);
        }

        // ---- epilogue: bias, store, gn2 partials ----
#pragma unroll
        for (int rt = 0; rt < 2; ++rt)
#pragma unroll
        for (int ct = 0; ct < 4; ++ct)
#pragma unroll
        for (int q = 0; q < 4; ++q) {
            int c = 32*w + 16*rt + 4*kg + q;
            float o = oacc[rt][ct][q] + bo[rt][q];
            out[((size_t)(b*CH + c) << 16) + n0 + 16*ct + ncol] = o;
            pgs[rt] += o;
            pgq[rt] += o*o;
        }
        __syncthreads();                 // xk reads done before next tile's staging
    }

    // ---- gn2 partial write: group = c>>2 = 8w+4rt+kg ----
#pragma unroll
    for (int rt = 0; rt < 2; ++rt) {
        float gs = pgs[rt], gq = pgq[rt];
#pragma unroll
        for (int m = 1; m < 16; m <<= 1) {
            gs += __shfl_xor(gs, m);
            gq += __shfl_xor(gq, m);
        }
        if (ncol == 0) {
            int g = 8*w + 4*rt + kg;
            part2[blockIdx.x*64 + g*2 + 0] = gs;
            part2[blockIdx.x*64 + g*2 + 1] = gq;
        }
    }
}

// ---------------- gn2 finalize (512 out_pass blocks -> 64 group stats) -----------------
__global__ __launch_bounds__(256) void reduce2(const float* __restrict__ part2,
                                               float* __restrict__ mu, float* __restrict__ rs) {
    __shared__ float s1[256], s2[256];
    int fg = blockIdx.x;          // 0..63
    int b = fg >> 5, g = fg & 31;
    int t = threadIdx.x;
    const float* p = part2 + ((size_t)(b*256 + t))*64 + g*2;
    s1[t] = p[0]; s2[t] = p[1];
    __syncthreads();
    for (int st = 128; st > 0; st >>= 1) {
        if (t < st) { s1[t] += s1[t + st]; s2[t] += s2[t + st]; }
        __syncthreads();
    }
    if (t == 0) {
        float m = s1[0] * (1.f / GSIZE);
        float v = s2[0] * (1.f / GSIZE) - m*m;
        mu[fg] = m; rs[fg] = rsqrtf(v + EPSV);
    }
}

__global__ __launch_bounds__(256) void gn_apply(float* __restrict__ y,
        const float* __restrict__ mu, const float* __restrict__ rs,
        const float* __restrict__ w2, const float* __restrict__ b2) {
    int bi = blockIdx.x, t = threadIdx.x;
    int c = (bi >> 3) & 127;
    int b = bi >> 10;
    int fg = b*32 + (c >> 2);
    float aa = rs[fg] * w2[c];
    float bb = b2[c] - mu[fg] * aa;
    float4* yp = (float4*)(y + (size_t)bi * 8192);
#pragma unroll
    for (int i = 0; i < 8; ++i) {
        float4 v = yp[t + 256*i];
        v.x = v.x*aa+bb; v.y = v.y*aa+bb; v.z = v.z*aa+bb; v.w = v.w*aa+bb;
        yp[t + 256*i] = v;
    }
}

extern "C" void kernel_launch(void* const* d_in, const int* in_sizes, int n_in,
                              void* d_out, int out_size, void* d_ws, size_t ws_size,
                              hipStream_t stream) {
    (void)in_sizes; (void)n_in; (void)out_size; (void)ws_size;
    const float* x      = (const float*)d_in[0];
    const float* n1w    = (const float*)d_in[1];
    const float* n1b    = (const float*)d_in[2];
    const float* w_qkv  = (const float*)d_in[3];
    const float* mem_kv = (const float*)d_in[4];
    const float* w_out  = (const float*)d_in[5];
    const float* b_out  = (const float*)d_in[6];
    const float* n2w    = (const float*)d_in[7];
    const float* n2b    = (const float*)d_in[8];
    float* out = (float*)d_out;
    float* ws  = (float*)d_ws;

    float* part1   = ws;              // 4096
    float* mu1     = ws + 4096;       // 64
    float* rs1     = ws + 4160;       // 64
    float* ctx     = ws + 4224;       // 8192
    float* Z       = ws + 12416;      // 256
    float* part2   = ws + 12672;      // 512*64 = 32768 (region reserves 131072)
    float* mu2     = ws + 143744;     // 64
    float* rs2     = ws + 143808;     // 64
    float* part_kv = ws + 143872;     // 512*4224 = 2162688  (total ~9.2 MB)

    gn_partial<<<2048, 256, 0, stream>>>(x, part1);
    prep1<<<1, 64, 0, stream>>>(part1, mu1, rs1);
    kv_pass<<<512, 256, 0, stream>>>(x, w_qkv, n1w, n1b, mu1, rs1, part_kv);
    reduce_ctx<<<33, 256, 0, stream>>>(part_kv, mem_kv, ctx, Z);
    out_pass<<<512, 256, 0, stream>>>(x, w_qkv, n1w, n1b, mu1, rs1, ctx, Z, w_out, b_out, out, part2);
    reduce2<<<64, 256, 0, stream>>>(part2, mu2, rs2);
    gn_apply<<<2048, 256, 0, stream>>>(out, mu2, rs2, n2w, n2b);
}

// Round 8
// 154.548 us; speedup vs baseline: 3.4286x; 1.0560x over previous
//
#include <hip/hip_runtime.h>
#include <math.h>

#define CH     128
#define EPSV   1e-5f
#define SCALE  0.17677669529663687f   // 32^-0.5
#define GSIZE  262144.0f

typedef short bf16x8 __attribute__((ext_vector_type(8)));
typedef short bf16x4 __attribute__((ext_vector_type(4)));
typedef float f32x4  __attribute__((ext_vector_type(4)));

__device__ __forceinline__ unsigned short f2bf(float f) {
    unsigned u = __float_as_uint(f);
    u += 0x7FFF + ((u >> 16) & 1);          // RNE
    return (unsigned short)(u >> 16);
}
__device__ __forceinline__ float bf2f(short s) {
    return __uint_as_float(((unsigned)(unsigned short)s) << 16);
}

// ---------------- group-norm partial stats (2048 blocks x 8192 elems) ----------------
__global__ __launch_bounds__(256) void gn_partial(const float* __restrict__ x,
                                                  float* __restrict__ part) {
    __shared__ float s1[256], s2[256];
    int t = threadIdx.x;
    const float4* xp = (const float4*)(x + (size_t)blockIdx.x * 8192);
    float s = 0.f, q = 0.f;
#pragma unroll
    for (int i = 0; i < 8; ++i) {
        float4 v = xp[t + 256 * i];
        s += v.x + v.y + v.z + v.w;
        q += v.x * v.x + v.y * v.y + v.z * v.z + v.w * v.w;
    }
    s1[t] = s; s2[t] = q;
    __syncthreads();
    for (int st = 128; st > 0; st >>= 1) {
        if (t < st) { s1[t] += s1[t + st]; s2[t] += s2[t + st]; }
        __syncthreads();
    }
    if (t == 0) { part[2 * blockIdx.x] = s1[0]; part[2 * blockIdx.x + 1] = s2[0]; }
}

// ---------------- finalize gn1 stats ---------------------------------------------------
__global__ void prep1(const float* __restrict__ part, float* __restrict__ mu, float* __restrict__ rs) {
    int t = threadIdx.x;   // 64 threads
    float s = 0.f, q = 0.f;
    for (int i = 0; i < 32; ++i) { s += part[2*(t*32+i)]; q += part[2*(t*32+i)+1]; }
    float m = s * (1.f / GSIZE);
    float v = q * (1.f / GSIZE) - m * m;
    mu[t] = m; rs[t] = rsqrtf(v + EPSV);
}

// ---------------- k/v pass (MFMA, pipelined): 2 barriers/tile --------------------------
// grid 512 x 256thr (4 waves). Block bi: tiles bi*4..bi*4+3, batch bi>>8.
// Wave w: kv-GEMM rows 64w..64w+63 (waves 0-1 = K -> exp, 2-3 = V); ctx head h = w.
// Pipeline: phase A {kvGEMM, exp/cvt->kvstage}; phase B {issue x(t+1) loads, ctx MFMA+Z,
// cvt+write xk(t+1)}. NOTE: no min-occupancy arg (R2-R4: VGPR caps -> spills).
__global__ __launch_bounds__(256) void kv_pass(const float* __restrict__ x,
        const float* __restrict__ w_qkv,
        const float* __restrict__ n1w, const float* __restrict__ n1b,
        const float* __restrict__ mu, const float* __restrict__ rs,
        float* __restrict__ part_kv) {
    __shared__ short xk[16*64*8];        // bf16 [ch>>3][n][ch&7]  (16 KB)
    __shared__ short kvstage[8*256*8];   // bf16 [n>>3][row][n&7], bytes^((row>>2)&3)<<4 (32 KB)
    int tid = threadIdx.x;
    int l = tid & 63, w = tid >> 6;
    int ncol = l & 15, kg = l >> 4;
    int b = blockIdx.x >> 8;
    int h = w;

    // ---- persistent A-fragments: W k/v rows (bf16), loaded once ----
    bf16x8 afrag[4][4];                  // [row-tile][k-step]
    {
        int row0 = 128 + w*64 + ncol;
        int k0   = 8 * kg;
#pragma unroll
        for (int rt = 0; rt < 4; ++rt)
#pragma unroll
        for (int ks = 0; ks < 4; ++ks) {
            const float* p = w_qkv + (size_t)(row0 + 16*rt)*CH + k0 + 32*ks;
            float4 u0 = *(const float4*)p;
            float4 u1 = *(const float4*)(p + 4);
            bf16x8 f;
            f[0]=(short)f2bf(u0.x); f[1]=(short)f2bf(u0.y); f[2]=(short)f2bf(u0.z); f[3]=(short)f2bf(u0.w);
            f[4]=(short)f2bf(u1.x); f[5]=(short)f2bf(u1.y); f[6]=(short)f2bf(u1.z); f[7]=(short)f2bf(u1.w);
            afrag[rt][ks] = f;
        }
    }

    // ---- persistent GN scale/shift for this thread's 8 staging channels ----
    int nst = (tid & 15) * 4;            // 4 positions
    int cst = (tid >> 4) * 8;            // 8-channel octet
    float aa[8], bb[8];
#pragma unroll
    for (int i = 0; i < 8; ++i) {
        int c = cst + i;
        int fg = b*32 + (c >> 2);
        float a0 = rs[fg] * n1w[c];
        aa[i] = a0;
        bb[i] = n1b[c] - mu[fg] * a0;
    }

    f32x4 cc[2][2];                      // ctx accumulator (head h), persists across tiles
#pragma unroll
    for (int i = 0; i < 2; ++i)
#pragma unroll
    for (int j = 0; j < 2; ++j)
#pragma unroll
    for (int q = 0; q < 4; ++q) cc[i][j][q] = 0.f;
    float zacc = 0.f;

    float4 xv[8];
    // ---- prologue: load + cvt + write tile 0 ----
    {
        int n0 = ((blockIdx.x * 4) << 6) & 65535;
#pragma unroll
        for (int i = 0; i < 8; ++i)
            xv[i] = *(const float4*)(x + ((size_t)(b*CH + cst + i) << 16) + n0 + nst);
        const float* xf = (const float*)xv;
#pragma unroll
        for (int j = 0; j < 4; ++j) {
            bf16x8 f;
#pragma unroll
            for (int i = 0; i < 8; ++i)
                f[i] = (short)f2bf(xf[i*4 + j] * aa[i] + bb[i]);
            *(bf16x8*)&xk[((cst >> 3)*64 + nst + j) * 8] = f;
        }
    }

    for (int t4 = 0; t4 < 4; ++t4) {
        __syncthreads();                 // xk(t4) ready; kvstage free (prev ctx reads done)

        // ---- phase A: kv GEMM (64 MFMA / wave) ----
        f32x4 acc[4][4];
#pragma unroll
        for (int i = 0; i < 4; ++i)
#pragma unroll
        for (int j = 0; j < 4; ++j)
#pragma unroll
        for (int q = 0; q < 4; ++q) acc[i][j][q] = 0.f;

#pragma unroll
        for (int ks = 0; ks < 4; ++ks) {
            bf16x8 bfr[4];
#pragma unroll
            for (int ct = 0; ct < 4; ++ct)
                bfr[ct] = *(bf16x8*)&xk[((4*ks + kg)*64 + 16*ct + ncol) * 8];
#pragma unroll
            for (int rt = 0; rt < 4; ++rt)
#pragma unroll
            for (int ct = 0; ct < 4; ++ct)
                acc[rt][ct] = __builtin_amdgcn_mfma_f32_16x16x32_bf16(
                    afrag[rt][ks], bfr[ct], acc[rt][ct], 0, 0, 0);
        }

        // ---- exp(K)/V -> kvstage (bf16, swizzled). C layout: col=l&15, row=4*(l>>4)+reg
#pragma unroll
        for (int rt = 0; rt < 4; ++rt)
#pragma unroll
        for (int ct = 0; ct < 4; ++ct)
#pragma unroll
        for (int q = 0; q < 4; ++q) {
            float v = acc[rt][ct][q];
            if (w < 2) v = __expf(v);
            int row = w*64 + 16*rt + 4*kg + q;
            int n   = 16*ct + ncol;
            int byteoff = ((n >> 3)*4096 + row*16 + (n & 7)*2) ^ (((row >> 2) & 3) << 4);
            *(short*)((char*)kvstage + byteoff) = (short)f2bf(v);
        }
        __syncthreads();                 // kvstage ready; xk reads done -> xk free

        // ---- phase B: issue next tile's loads first (latency hides under ctx MFMA) ----
        if (t4 < 3) {
            int n0 = ((blockIdx.x * 4 + t4 + 1) << 6) & 65535;
#pragma unroll
            for (int i = 0; i < 8; ++i)
                xv[i] = *(const float4*)(x + ((size_t)(b*CH + cst + i) << 16) + n0 + nst);
        }

        // ---- ctx MFMA: head h, ctx += expK(32x64) @ V^T(64x32) ----
#pragma unroll
        for (int ks = 0; ks < 2; ++ks) {
            bf16x8 ak[2], bv[2];
#pragma unroll
            for (int rt = 0; rt < 2; ++rt) {
                int row = h*32 + 16*rt + ncol;
                int byteoff = ((4*ks + kg)*4096 + row*16) ^ (((row >> 2) & 3) << 4);
                ak[rt] = *(bf16x8*)((char*)kvstage + byteoff);
            }
#pragma unroll
            for (int ct = 0; ct < 2; ++ct) {
                int row = 128 + h*32 + 16*ct + ncol;
                int byteoff = ((4*ks + kg)*4096 + row*16) ^ (((row >> 2) & 3) << 4);
                bv[ct] = *(bf16x8*)((char*)kvstage + byteoff);
            }
#pragma unroll
            for (int rt = 0; rt < 2; ++rt)
#pragma unroll
            for (int ct = 0; ct < 2; ++ct)
                cc[rt][ct] = __builtin_amdgcn_mfma_f32_16x16x32_bf16(
                    ak[rt], bv[ct], cc[rt][ct], 0, 0, 0);
        }
        // ---- Z partial: lane (d=l&31, half=l>>5) sums expK row over 32 n ----
        {
            int d = l & 31, nh = l >> 5;
            int row = h*32 + d;
#pragma unroll
            for (int q = 0; q < 4; ++q) {
                int byteoff = (((nh*4 + q)*4096) + row*16) ^ (((row >> 2) & 3) << 4);
                bf16x8 e8 = *(bf16x8*)((char*)kvstage + byteoff);
#pragma unroll
                for (int j = 0; j < 8; ++j) zacc += bf2f(e8[j]);
            }
        }

        // ---- cvt + write xk(t4+1) ----
        if (t4 < 3) {
            const float* xf = (const float*)xv;
#pragma unroll
            for (int j = 0; j < 4; ++j) {
                bf16x8 f;
#pragma unroll
                for (int i = 0; i < 8; ++i)
                    f[i] = (short)f2bf(xf[i*4 + j] * aa[i] + bb[i]);
                *(bf16x8*)&xk[((cst >> 3)*64 + nst + j) * 8] = f;
            }
        }
    }

    // ---- streaming partial write ----
    float* dst = part_kv + (size_t)blockIdx.x * 4224;
#pragma unroll
    for (int rt = 0; rt < 2; ++rt)
#pragma unroll
    for (int ct = 0; ct < 2; ++ct)
#pragma unroll
    for (int q = 0; q < 4; ++q) {
        int d = 16*rt + 4*kg + q;
        int e = 16*ct + ncol;
        dst[h*1024 + d*32 + e] = cc[rt][ct][q];
    }
    float zs = zacc + __shfl_down(zacc, 32);
    if (l < 32) dst[4096 + h*32 + l] = zs;
}

// ---------------- reduce partials + memory-kv init -> ctx, Z ---------------------------
__global__ void reduce_ctx(const float* __restrict__ part_kv, const float* __restrict__ mem_kv,
                           float* __restrict__ ctx, float* __restrict__ Z) {
    int gid = blockIdx.x * 256 + threadIdx.x;   // 0..8447
    int b = gid / 4224;
    int e = gid - b * 4224;
    const float* p = part_kv + (size_t)b * 256 * 4224 + e;
    float s0 = 0.f, s1 = 0.f, s2 = 0.f, s3 = 0.f;
    for (int i = 0; i < 256; i += 4) {
        s0 += p[(i+0)*4224];
        s1 += p[(i+1)*4224];
        s2 += p[(i+2)*4224];
        s3 += p[(i+3)*4224];
    }
    float s = (s0 + s1) + (s2 + s3);
    if (e < 4096) {
        int hh = e >> 10, d = (e >> 5) & 31, ee = e & 31;
        float init = 0.f;
        for (int m = 0; m < 4; ++m)
            init += expf(mem_kv[hh*128 + d*4 + m]) * mem_kv[512 + hh*128 + ee*4 + m];
        ctx[b*4096 + e] = init + s;
    } else {
        int d2 = e - 4096;
        float init = 0.f;
        for (int m = 0; m < 4; ++m) init += expf(mem_kv[d2*4 + m]);
        Z[b*128 + d2] = init + s;
    }
}

// ---------------- out pass (MFMA, pipelined): 2 barriers/tile --------------------------
// grid 1024 x 256thr (4 waves). Block bi: tiles bi*2, bi*2+1; batch bi>>9.
// Wave w: head w; output rows 32w..32w+31. xk = x tile; pb = qprob/hid buffer.
// qprob/hid rows of wave w are wave-private (in-order DS pipe -> no barrier inside A).
// NOTE: no min-occupancy arg (R2-R4: VGPR caps -> spills).
__global__ __launch_bounds__(256) void out_pass(const float* __restrict__ x,
        const float* __restrict__ w_qkv,
        const float* __restrict__ n1w, const float* __restrict__ n1b,
        const float* __restrict__ mu, const float* __restrict__ rs,
        const float* __restrict__ ctx, const float* __restrict__ Z,
        const float* __restrict__ w_out, const float* __restrict__ b_out,
        float* __restrict__ out, float* __restrict__ part2) {
    __shared__ short xk[16*64*8];        // bf16 [row>>3][n][row&7]  (16 KB)
    __shared__ short pb[16*64*8];        // bf16 qprob/hid buffer    (16 KB)
    int tid = threadIdx.x;
    int l = tid & 63, w = tid >> 6;
    int ncol = l & 15, kg = l >> 4;
    int b = blockIdx.x >> 9;

    // ---- persistent A-fragments: W_q and W_out rows 32w..32w+31 ----
    bf16x8 aq[2][4], aw[2][4];
#pragma unroll
    for (int rt = 0; rt < 2; ++rt)
#pragma unroll
    for (int ks = 0; ks < 4; ++ks) {
        const float* pq = w_qkv + (size_t)(32*w + 16*rt + ncol)*CH + 8*kg + 32*ks;
        const float* pw = w_out + (size_t)(32*w + 16*rt + ncol)*CH + 8*kg + 32*ks;
        float4 u0 = *(const float4*)pq, u1 = *(const float4*)(pq + 4);
        float4 v0 = *(const float4*)pw, v1 = *(const float4*)(pw + 4);
        bf16x8 fq, fw;
        fq[0]=(short)f2bf(u0.x); fq[1]=(short)f2bf(u0.y); fq[2]=(short)f2bf(u0.z); fq[3]=(short)f2bf(u0.w);
        fq[4]=(short)f2bf(u1.x); fq[5]=(short)f2bf(u1.y); fq[6]=(short)f2bf(u1.z); fq[7]=(short)f2bf(u1.w);
        fw[0]=(short)f2bf(v0.x); fw[1]=(short)f2bf(v0.y); fw[2]=(short)f2bf(v0.z); fw[3]=(short)f2bf(v0.w);
        fw[4]=(short)f2bf(v1.x); fw[5]=(short)f2bf(v1.y); fw[6]=(short)f2bf(v1.z); fw[7]=(short)f2bf(v1.w);
        aq[rt][ks] = fq;
        aw[rt][ks] = fw;
    }

    // ---- persistent A-frag: normalized ctx^T (row e, k=d) for head w ----
    bf16x8 actx[2];
#pragma unroll
    for (int rt = 0; rt < 2; ++rt) {
        bf16x8 f;
#pragma unroll
        for (int j = 0; j < 8; ++j) {
            int d = 8*kg + j;
            float cv = ctx[b*4096 + w*1024 + d*32 + 16*rt + ncol] / Z[b*128 + w*32 + d];
            f[j] = (short)f2bf(cv);
        }
        actx[rt] = f;
    }

    // ---- persistent epilogue bias ----
    float bo[2][4];
#pragma unroll
    for (int rt = 0; rt < 2; ++rt)
#pragma unroll
    for (int q = 0; q < 4; ++q)
        bo[rt][q] = b_out[32*w + 16*rt + 4*kg + q];

    // ---- persistent GN scale/shift for staging channels ----
    int nst = (tid & 15) * 4;
    int cst = (tid >> 4) * 8;
    float aa[8], bb[8];
#pragma unroll
    for (int i = 0; i < 8; ++i) {
        int c = cst + i;
        int fg = b*32 + (c >> 2);
        float a0 = rs[fg] * n1w[c];
        aa[i] = a0;
        bb[i] = n1b[c] - mu[fg] * a0;
    }

    float pgs[2] = {0.f, 0.f}, pgq[2] = {0.f, 0.f};   // gn2 partials
    float4 xv[8];

    // ---- prologue: load + cvt + write tile 0 ----
    {
        int n0 = ((blockIdx.x * 2) << 6) & 65535;
#pragma unroll
        for (int i = 0; i < 8; ++i)
            xv[i] = *(const float4*)(x + ((size_t)(b*CH + cst + i) << 16) + n0 + nst);
        const float* xf = (const float*)xv;
#pragma unroll
        for (int j = 0; j < 4; ++j) {
            bf16x8 f;
#pragma unroll
            for (int i = 0; i < 8; ++i)
                f[i] = (short)f2bf(xf[i*4 + j] * aa[i] + bb[i]);
            *(bf16x8*)&xk[((cst >> 3)*64 + nst + j) * 8] = f;
        }
    }

    for (int t2 = 0; t2 < 2; ++t2) {
        int n0 = ((blockIdx.x * 2 + t2) << 6) & 65535;
        __syncthreads();                 // xk(t2) ready; pb free (prev wout reads done)

        // ---- q GEMM: 32 MFMA / wave ----
        f32x4 acc[2][4];
#pragma unroll
        for (int i = 0; i < 2; ++i)
#pragma unroll
        for (int j = 0; j < 4; ++j)
#pragma unroll
        for (int q = 0; q < 4; ++q) acc[i][j][q] = 0.f;
#pragma unroll
        for (int ks = 0; ks < 4; ++ks) {
            bf16x8 bfr[4];
#pragma unroll
            for (int ct = 0; ct < 4; ++ct)
                bfr[ct] = *(bf16x8*)&xk[((4*ks + kg)*64 + 16*ct + ncol) * 8];
#pragma unroll
            for (int rt = 0; rt < 2; ++rt)
#pragma unroll
            for (int ct = 0; ct < 4; ++ct)
                acc[rt][ct] = __builtin_amdgcn_mfma_f32_16x16x32_bf16(
                    aq[rt][ks], bfr[ct], acc[rt][ct], 0, 0, 0);
        }

        // ---- softmax over d (32/head) per column; write qprob -> pb (own-wave rows) ----
        {
            float sum[4];
#pragma unroll
            for (int ct = 0; ct < 4; ++ct) {
                float s = 0.f;
#pragma unroll
                for (int rt = 0; rt < 2; ++rt)
#pragma unroll
                for (int q = 0; q < 4; ++q) {
                    float e = __expf(acc[rt][ct][q]);
                    acc[rt][ct][q] = e;
                    s += e;
                }
                s += __shfl_xor(s, 16);
                s += __shfl_xor(s, 32);
                sum[ct] = SCALE / s;
            }
#pragma unroll
            for (int ct = 0; ct < 4; ++ct)
#pragma unroll
            for (int rt = 0; rt < 2; ++rt) {
                bf16x4 pk;
#pragma unroll
                for (int q = 0; q < 4; ++q) pk[q] = (short)f2bf(acc[rt][ct][q] * sum[ct]);
                int row0 = w*32 + 16*rt + 4*kg;
                *(bf16x4*)&pb[((row0 >> 3)*64 + 16*ct + ncol)*8 + (row0 & 7)] = pk;
            }
        }

        // ---- hid GEMM (own-wave pb reads; DS pipe is in-order per wave) ----
        f32x4 hacc[2][4];
#pragma unroll
        for (int i = 0; i < 2; ++i)
#pragma unroll
        for (int j = 0; j < 4; ++j)
#pragma unroll
        for (int q = 0; q < 4; ++q) hacc[i][j][q] = 0.f;
        {
            bf16x8 bq[4];
#pragma unroll
            for (int ct = 0; ct < 4; ++ct)
                bq[ct] = *(bf16x8*)&pb[((w*4 + kg)*64 + 16*ct + ncol) * 8];
#pragma unroll
            for (int rt = 0; rt < 2; ++rt)
#pragma unroll
            for (int ct = 0; ct < 4; ++ct)
                hacc[rt][ct] = __builtin_amdgcn_mfma_f32_16x16x32_bf16(
                    actx[rt], bq[ct], hacc[rt][ct], 0, 0, 0);
        }

        // ---- write hid -> pb (same own-wave rows; WAR safe in-order) ----
#pragma unroll
        for (int ct = 0; ct < 4; ++ct)
#pragma unroll
        for (int rt = 0; rt < 2; ++rt) {
            bf16x4 pk;
#pragma unroll
            for (int q = 0; q < 4; ++q) pk[q] = (short)f2bf(hacc[rt][ct][q]);
            int row0 = w*32 + 16*rt + 4*kg;
            *(bf16x4*)&pb[((row0 >> 3)*64 + 16*ct + ncol)*8 + (row0 & 7)] = pk;
        }
        __syncthreads();                 // pb(hid) ready; xk reads done -> xk free

        // ---- phase B: issue next tile's loads first ----
        if (t2 == 0) {
            int n1 = ((blockIdx.x * 2 + 1) << 6) & 65535;
#pragma unroll
            for (int i = 0; i < 8; ++i)
                xv[i] = *(const float4*)(x + ((size_t)(b*CH + cst + i) << 16) + n1 + nst);
        }

        // ---- w_out GEMM: 32 MFMA / wave ----
        f32x4 oacc[2][4];
#pragma unroll
        for (int i = 0; i < 2; ++i)
#pragma unroll
        for (int j = 0; j < 4; ++j)
#pragma unroll
        for (int q = 0; q < 4; ++q) oacc[i][j][q] = 0.f;
#pragma unroll
        for (int ks = 0; ks < 4; ++ks) {
            bf16x8 bfr[4];
#pragma unroll
            for (int ct = 0; ct < 4; ++ct)
                bfr[ct] = *(bf16x8*)&pb[((4*ks + kg)*64 + 16*ct + ncol) * 8];
#pragma unroll
            for (int rt = 0; rt < 2; ++rt)
#pragma unroll
            for (int ct = 0; ct < 4; ++ct)
                oacc[rt][ct] = __builtin_amdgcn_mfma_f32_16x16x32_bf16(
                    aw[rt][ks], bfr[ct], oacc[rt][ct], 0, 0, 0);
        }

        // ---- epilogue: bias, store, gn2 partials ----
#pragma unroll
        for (int rt = 0; rt < 2; ++rt)
#pragma unroll
        for (int ct = 0; ct < 4; ++ct)
#pragma unroll
        for (int q = 0; q < 4; ++q) {
            int c = 32*w + 16*rt + 4*kg + q;
            float o = oacc[rt][ct][q] + bo[rt][q];
            out[((size_t)(b*CH + c) << 16) + n0 + 16*ct + ncol] = o;
            pgs[rt] += o;
            pgq[rt] += o*o;
        }

        // ---- cvt + write xk(t2+1) ----
        if (t2 == 0) {
            const float* xf = (const float*)xv;
#pragma unroll
            for (int j = 0; j < 4; ++j) {
                bf16x8 f;
#pragma unroll
                for (int i = 0; i < 8; ++i)
                    f[i] = (short)f2bf(xf[i*4 + j] * aa[i] + bb[i]);
                *(bf16x8*)&xk[((cst >> 3)*64 + nst + j) * 8] = f;
            }
        }
    }

    // ---- gn2 partial write: group = c>>2 = 8w+4rt+kg ----
#pragma unroll
    for (int rt = 0; rt < 2; ++rt) {
        float gs = pgs[rt], gq = pgq[rt];
#pragma unroll
        for (int m = 1; m < 16; m <<= 1) {
            gs += __shfl_xor(gs, m);
            gq += __shfl_xor(gq, m);
        }
        if (ncol == 0) {
            int g = 8*w + 4*rt + kg;
            part2[blockIdx.x*64 + g*2 + 0] = gs;
            part2[blockIdx.x*64 + g*2 + 1] = gq;
        }
    }
}

// ---------------- gn2 finalize (1024 out_pass blocks -> 64 group stats) ----------------
__global__ __launch_bounds__(256) void reduce2(const float* __restrict__ part2,
                                               float* __restrict__ mu, float* __restrict__ rs) {
    __shared__ float s1[256], s2[256];
    int fg = blockIdx.x;          // 0..63
    int b = fg >> 5, g = fg & 31;
    int t = threadIdx.x;
    float s = 0.f, q = 0.f;
    for (int i = t; i < 512; i += 256) {
        const float* p = part2 + ((size_t)(b*512 + i))*64 + g*2;
        s += p[0]; q += p[1];
    }
    s1[t] = s; s2[t] = q;
    __syncthreads();
    for (int st = 128; st > 0; st >>= 1) {
        if (t < st) { s1[t] += s1[t + st]; s2[t] += s2[t + st]; }
        __syncthreads();
    }
    if (t == 0) {
        float m = s1[0] * (1.f / GSIZE);
        float v = s2[0] * (1.f / GSIZE) - m*m;
        mu[fg] = m; rs[fg] = rsqrtf(v + EPSV);
    }
}

__global__ __launch_bounds__(256) void gn_apply(float* __restrict__ y,
        const float* __restrict__ mu, const float* __restrict__ rs,
        const float* __restrict__ w2, const float* __restrict__ b2) {
    int bi = blockIdx.x, t = threadIdx.x;
    int c = (bi >> 3) & 127;
    int b = bi >> 10;
    int fg = b*32 + (c >> 2);
    float aa = rs[fg] * w2[c];
    float bb = b2[c] - mu[fg] * aa;
    float4* yp = (float4*)(y + (size_t)bi * 8192);
#pragma unroll
    for (int i = 0; i < 8; ++i) {
        float4 v = yp[t + 256*i];
        v.x = v.x*aa+bb; v.y = v.y*aa+bb; v.z = v.z*aa+bb; v.w = v.w*aa+bb;
        yp[t + 256*i] = v;
    }
}

extern "C" void kernel_launch(void* const* d_in, const int* in_sizes, int n_in,
                              void* d_out, int out_size, void* d_ws, size_t ws_size,
                              hipStream_t stream) {
    (void)in_sizes; (void)n_in; (void)out_size; (void)ws_size;
    const float* x      = (const float*)d_in[0];
    const float* n1w    = (const float*)d_in[1];
    const float* n1b    = (const float*)d_in[2];
    const float* w_qkv  = (const float*)d_in[3];
    const float* mem_kv = (const float*)d_in[4];
    const float* w_out  = (const float*)d_in[5];
    const float* b_out  = (const float*)d_in[6];
    const float* n2w    = (const float*)d_in[7];
    const float* n2b    = (const float*)d_in[8];
    float* out = (float*)d_out;
    float* ws  = (float*)d_ws;

    float* part1   = ws;              // 4096
    float* mu1     = ws + 4096;       // 64
    float* rs1     = ws + 4160;       // 64
    float* ctx     = ws + 4224;       // 8192
    float* Z       = ws + 12416;      // 256
    float* part2   = ws + 12672;      // 1024*64 = 65536 (region reserves 131072)
    float* mu2     = ws + 143744;     // 64
    float* rs2     = ws + 143808;     // 64
    float* part_kv = ws + 143872;     // 512*4224 = 2162688  (total ~9.2 MB)

    gn_partial<<<2048, 256, 0, stream>>>(x, part1);
    prep1<<<1, 64, 0, stream>>>(part1, mu1, rs1);
    kv_pass<<<512, 256, 0, stream>>>(x, w_qkv, n1w, n1b, mu1, rs1, part_kv);
    reduce_ctx<<<33, 256, 0, stream>>>(part_kv, mem_kv, ctx, Z);
    out_pass<<<1024, 256, 0, stream>>>(x, w_qkv, n1w, n1b, mu1, rs1, ctx, Z, w_out, b_out, out, part2);
    reduce2<<<64, 256, 0, stream>>>(part2, mu2, rs2);
    gn_apply<<<2048, 256, 0, stream>>>(out, mu2, rs2, n2w, n2b);
}